// Round 11
// baseline (449.166 us; speedup 1.0000x reference)
//
#include <hip/hip_runtime.h>

#define KN 100000
#define KEG 600000
#define KE 600000
#define NB 98  // ceil(KN/1024) scan blocks
#define LOG2E 1.4426950408889634f
#define LN2 0.6931471805599453f

// k_front block ranges
#define FB_PREP 391
#define FB_CVEC 33
#define FB_HIST 2344
#define FB_T0 25000

using u16 = unsigned short;
typedef __bf16 bf16x8 __attribute__((ext_vector_type(8)));
typedef float f32x4 __attribute__((ext_vector_type(4)));
typedef float f32x2 __attribute__((ext_vector_type(2)));

__device__ __forceinline__ float b2f(u16 u) { return __uint_as_float(((unsigned)u) << 16); }
__device__ __forceinline__ u16 f2b(float f) {
  unsigned u = __float_as_uint(f);
  u += 0x7FFF + ((u >> 16) & 1);  // round-to-nearest-even
  return (u16)(u >> 16);
}
__device__ __forceinline__ int imin(int a, int b) { return a < b ? a : b; }
__device__ __forceinline__ float fexp2(float x) {
#if __has_builtin(__builtin_amdgcn_exp2f)
  return __builtin_amdgcn_exp2f(x);
#else
  return __expf(x * LN2);
#endif
}

// ---------------- fused front: prep + cvec + hist + transform0 ----------------
// wm1t: 36 tiles x 5 frags x 512 (tiles 34..35 = staging pad, never computed).
// Tiles 0..32: Wm1 rows 0..127 (frags 0..3) and K-ext rows [w128,w129,bm1]
// (frag 4), ALL x LOG2E. Tile 33 (owned by cvec range): linear composite
// c=B160@wm2 natural units, c_hi col0 / c_lo col1.
__global__ __launch_bounds__(256) void k_front(
    const float* __restrict__ pos, const float* __restrict__ W0,
    const float* __restrict__ att_s, const float* __restrict__ att_d,
    const float* __restrict__ wm1, const float* __restrict__ bm1,
    const float* __restrict__ wm2, const float* __restrict__ w1,
    const int* __restrict__ gdst,
    u16* __restrict__ wm1t, u16* __restrict__ w1t, float2* __restrict__ wsc2,
    float* __restrict__ w2sum, int* __restrict__ counts,
    u16* __restrict__ h, float* __restrict__ a_s, float* __restrict__ a_d) {
  int bid = blockIdx.x;
  if (bid < FB_PREP) {
    int idx = bid * 256 + threadIdx.x;
    if (idx < 33 * 5 * 512) {  // tiles 0..32 only
      int j = idx & 7;
      int lane = (idx >> 3) & 63;
      int f = (idx >> 9) % 5;
      int nt = idx / (512 * 5);
      int n = nt * 16 + (lane & 15);
      float v = 0.f;
      if (n < 520) {
        if (f < 4) {
          int k = f * 32 + (lane >> 4) * 8 + j;
          v = wm1[k * 520 + n] * LOG2E;
        } else {
          int kk = (lane >> 4) * 8 + j;
          if (kk == 0) v = wm1[128 * 520 + n] * LOG2E;
          else if (kk == 1) v = wm1[129 * 520 + n] * LOG2E;
          else if (kk == 2) v = bm1[n] * LOG2E;
        }
      }
      wm1t[idx] = f2b(v);
    }
    if (idx < 33 * 64) {
      int lane = idx & 63, nt = idx >> 6;
      int col = nt * 16 + (lane & 15);
      float w2 = (col < 520) ? wm2[col] : 0.f;
      float2 p; p.x = w2; p.y = -LN2 * w2;
      wsc2[idx] = p;
    }
    if (idx < 4 * 2 * 64 * 8) {  // W1 -> MFMA B frags
      int j = idx & 7;
      int lane = (idx >> 3) & 63;
      int kt = (idx >> 9) & 1;
      int nt = idx >> 10;
      int n = nt * 16 + (lane & 15);
      int k = kt * 32 + (lane >> 4) * 8 + j;
      w1t[idx] = f2b(w1[k * 64 + n]);
    }
  } else if (bid < FB_PREP + FB_CVEC) {
    // cvec: c_k = sum_h B160[k][h]*wm2[h]; w = row index 0..130; w==131 -> w2sum
    int lane = threadIdx.x & 63;
    int w = (bid - FB_PREP) * 4 + (threadIdx.x >> 6);
    float x = 0.f;
    if (w <= 129) {
      const float* row = wm1 + (size_t)w * 520;
#pragma unroll
      for (int j = 0; j < 8; ++j) x += row[j * 64 + lane] * wm2[j * 64 + lane];
      if (lane < 8) x += row[512 + lane] * wm2[512 + lane];
    } else if (w == 130) {
#pragma unroll
      for (int j = 0; j < 8; ++j) x += bm1[j * 64 + lane] * wm2[j * 64 + lane];
      if (lane < 8) x += bm1[512 + lane] * wm2[512 + lane];
    } else if (w == 131) {
#pragma unroll
      for (int j = 0; j < 8; ++j) x += wm2[j * 64 + lane];
      if (lane < 8) x += wm2[512 + lane];
    }
    for (int off = 1; off < 64; off <<= 1) x += __shfl_xor(x, off);
    if (w <= 130 && lane < 16) {
      int f = w >> 5, kk = w & 31;
      int qq = kk >> 3, jj = kk & 7;
      u16 chi = f2b(x);
      float v = (lane == 0) ? x : (lane == 1 ? (x - b2f(chi)) : 0.f);
      wm1t[(33 * 5 + f) * 512 + (qq * 16 + lane) * 8 + jj] = f2b(v);
    } else if (w == 131 && lane == 0) {
      w2sum[0] = x;
    }
  } else if (bid < FB_PREP + FB_CVEC + FB_HIST) {
    int e = (bid - (FB_PREP + FB_CVEC)) * 256 + threadIdx.x;
    if (e < KEG) atomicAdd(counts + gdst[e], 1);
  } else {
    // transform0: h = pos @ W0, a_s/a_d reductions. 25000 blocks x 4 nodes.
    int lane = threadIdx.x & 63;
    int n = (bid - (FB_PREP + FB_CVEC + FB_HIST)) * 4 + (threadIdx.x >> 6);
    float p0 = pos[n * 3 + 0], p1 = pos[n * 3 + 1], p2 = pos[n * 3 + 2];
    float hv = p0 * W0[lane] + p1 * W0[64 + lane] + p2 * W0[128 + lane];
    h[n * 64 + lane] = f2b(hv);
    float s = hv * att_s[lane];
    float d = hv * att_d[lane];
    for (int off = 1; off < 64; off <<= 1) { s += __shfl_xor(s, off); d += __shfl_xor(d, off); }
    if (lane == 0) { a_s[n] = s; a_d[n] = d; }
  }
}

// ---------------- CSR build ----------------

__global__ __launch_bounds__(1024) void k_scan_block(
    const int* __restrict__ counts, int* __restrict__ incl, int* __restrict__ bsum) {
  int gid = blockIdx.x * 1024 + threadIdx.x;
  int lane = threadIdx.x & 63, w = threadIdx.x >> 6;
  int x = (gid < KN) ? counts[gid] : 0;
  for (int off = 1; off < 64; off <<= 1) {
    int y = __shfl_up(x, off);
    if (lane >= off) x += y;
  }
  __shared__ int wtot[16];
  if (lane == 63) wtot[w] = x;
  __syncthreads();
  if (w == 0 && lane < 16) {
    int t = wtot[lane];
    for (int off = 1; off < 16; off <<= 1) {
      int y = __shfl_up(t, off);
      if (lane >= off) t += y;
    }
    wtot[lane] = t;
  }
  __syncthreads();
  if (w > 0) x += wtot[w - 1];
  if (gid < KN) incl[gid] = x;
  if (threadIdx.x == 1023) bsum[blockIdx.x] = x;
}

__global__ __launch_bounds__(64) void k_scan_bsum(const int* __restrict__ bsum, int* __restrict__ boff) {
  int lane = threadIdx.x;
  int x0 = (lane < NB) ? bsum[lane] : 0;
  int x1 = (64 + lane < NB) ? bsum[64 + lane] : 0;
  int i0 = x0, i1 = x1;
  for (int off = 1; off < 64; off <<= 1) {
    int y0 = __shfl_up(i0, off), y1 = __shfl_up(i1, off);
    if (lane >= off) { i0 += y0; i1 += y1; }
  }
  int tot0 = __shfl(i0, 63);
  if (lane < NB) boff[lane] = i0 - x0;
  if (64 + lane < NB) boff[64 + lane] = i1 - x1 + tot0;
}

__global__ __launch_bounds__(1024) void k_scan_final(
    const int* __restrict__ incl, const int* __restrict__ counts,
    const int* __restrict__ boff, int* __restrict__ row_start) {
  int gid = blockIdx.x * 1024 + threadIdx.x;
  if (gid < KN) row_start[gid] = incl[gid] - counts[gid] + boff[blockIdx.x];
}

// fill CSR (src+dst) and layer-0 edge weights ew0=exp(leakyrelu(a_s+a_d))
__global__ __launch_bounds__(256) void k_fill(
    const int* __restrict__ gsrc, const int* __restrict__ gdst,
    const int* __restrict__ row_start, int* __restrict__ cursor,
    const float* __restrict__ a_s, const float* __restrict__ a_d,
    int* __restrict__ csr_src, int* __restrict__ csr_dst, float* __restrict__ ew) {
  int e = blockIdx.x * 256 + threadIdx.x;
  if (e >= KEG) return;
  int s = gsrc[e], d = gdst[e];
  int pos = atomicAdd(cursor + d, 1);
  int slot = row_start[d] + pos;
  csr_src[slot] = s;
  csr_dst[slot] = d;
  float al = a_s[s] + a_d[d];
  al = al > 0.f ? al : 0.2f * al;
  ew[slot] = __expf(al);
}

// layer-1 edge weights in CSR order
__global__ __launch_bounds__(256) void k_ew(
    const int* __restrict__ csr_src, const int* __restrict__ csr_dst,
    const float* __restrict__ a_s, const float* __restrict__ a_d, float* __restrict__ ew) {
  int slot = blockIdx.x * 256 + threadIdx.x;
  if (slot >= KEG) return;
  float al = a_s[csr_src[slot]] + a_d[csr_dst[slot]];
  al = al > 0.f ? al : 0.2f * al;
  ew[slot] = __expf(al);
}

// ---------------- GAT layers ----------------

// layer1 transform via MFMA: 16 nodes/wave, h = x @ W1 (64x64), fused a_s/a_d.
__global__ __launch_bounds__(256) void k_transform1(
    const u16* __restrict__ x, const u16* __restrict__ w1t,
    const float* __restrict__ att_s, const float* __restrict__ att_d,
    u16* __restrict__ h, float* __restrict__ a_s, float* __restrict__ a_d) {
  int lane = threadIdx.x & 63;
  int wave = threadIdx.x >> 6;
  int nodebase = blockIdx.x * 64 + wave * 16;
  int m = lane & 15, q = lane >> 4;

  int node = imin(nodebase + m, KN - 1);
  const bf16x8* px = (const bf16x8*)(x + node * 64);
  bf16x8 A0 = px[q];      // k 0..31
  bf16x8 A1 = px[q + 4];  // k 32..63

  const bf16x8* bt = (const bf16x8*)w1t;
  float ps[4] = {0.f, 0.f, 0.f, 0.f};
  float pd[4] = {0.f, 0.f, 0.f, 0.f};
#pragma unroll
  for (int nt = 0; nt < 4; ++nt) {
    int col = nt * 16 + m;
    float asv = att_s[col], adv = att_d[col];
    f32x4 acc = {0.f, 0.f, 0.f, 0.f};
    acc = __builtin_amdgcn_mfma_f32_16x16x32_bf16(A0, bt[(nt * 2 + 0) * 64 + lane], acc, 0, 0, 0);
    acc = __builtin_amdgcn_mfma_f32_16x16x32_bf16(A1, bt[(nt * 2 + 1) * 64 + lane], acc, 0, 0, 0);
#pragma unroll
    for (int r = 0; r < 4; ++r) {
      int rown = nodebase + q * 4 + r;
      if (rown < KN) h[rown * 64 + col] = f2b(acc[r]);
      ps[r] += acc[r] * asv;
      pd[r] += acc[r] * adv;
    }
  }
#pragma unroll
  for (int r = 0; r < 4; ++r) {
    float s = ps[r], d = pd[r];
    s += __shfl_xor(s, 1); d += __shfl_xor(d, 1);
    s += __shfl_xor(s, 2); d += __shfl_xor(d, 2);
    s += __shfl_xor(s, 4); d += __shfl_xor(d, 4);
    s += __shfl_xor(s, 8); d += __shfl_xor(d, 8);
    int rown = nodebase + q * 4 + r;
    if (m == 0 && rown < KN) { a_s[rown] = s; a_d[rown] = d; }
  }
}

// aggregate with precomputed weights: one wave per dst node, 4-way ILP unroll.
__global__ __launch_bounds__(256) void k_gat_agg(
    const int* __restrict__ row_start, const int* __restrict__ counts,
    const int* __restrict__ csr_src, const float* __restrict__ ew,
    const u16* __restrict__ h, const float* __restrict__ bias, u16* __restrict__ xout) {
  int lane = threadIdx.x & 63;
  int n = blockIdx.x * 4 + (threadIdx.x >> 6);  // grid covers KN exactly
  int start = row_start[n], deg = counts[n];
  float acc = 0.f, den = 0.f;
  int j = 0;
  for (; j + 4 <= deg; j += 4) {
    int s0 = csr_src[start + j];
    int s1 = csr_src[start + j + 1];
    int s2 = csr_src[start + j + 2];
    int s3 = csr_src[start + j + 3];
    float w0 = ew[start + j], w1 = ew[start + j + 1];
    float w2 = ew[start + j + 2], w3 = ew[start + j + 3];
    float h0 = b2f(h[s0 * 64 + lane]);
    float h1 = b2f(h[s1 * 64 + lane]);
    float h2 = b2f(h[s2 * 64 + lane]);
    float h3 = b2f(h[s3 * 64 + lane]);
    den += (w0 + w1) + (w2 + w3);
    acc += w0 * h0 + w1 * h1 + w2 * h2 + w3 * h3;
  }
  for (; j < deg; ++j) {
    int s0 = csr_src[start + j];
    float w0 = ew[start + j];
    den += w0;
    acc += w0 * b2f(h[s0 * 64 + lane]);
  }
  float v = acc / (den + 1e-16f) + bias[lane];
  v = v > 0.f ? v : expm1f(v);
  xout[n * 64 + lane] = f2b(v);
}

// ---------------- edge MLP ----------------
// Chunked LDS double-buffer: 4 nt-tiles (20 frags = 20 KB) per chunk, staged
// cooperatively (5 uint4/thread, globally contiguous), barrier once per chunk
// (9 total vs 33). Prefetch for chunk+1 issued before compute. Per element:
// t=min(acc2,0); e=exp2(t); osum += e*w2 + t*(-ln2*w2). Linear part via the
// precomputed composite tile 33 (c_hi col0 + c_lo col1).
__global__ __launch_bounds__(256) void k_edge_mlp(
    const int* __restrict__ eidx, const u16* __restrict__ x2bf,
    const float* __restrict__ eattr, const u16* __restrict__ wm1t,
    const float2* __restrict__ wsc2, const float* __restrict__ w2sum,
    const float* __restrict__ bm2, float* __restrict__ out) {
  __shared__ uint4 Bbuf[2][20 * 64];  // 40 KB
  int tid = threadIdx.x;
  int lane = tid & 63;
  int wave = tid >> 6;
  int base = blockIdx.x * 256 + wave * 64;
  int m = lane & 15, q = lane >> 4;

  // A fragments: A[m=lane&15][k=q*8+j]
  bf16x8 A[4][4];
#pragma unroll
  for (int s = 0; s < 4; ++s) {
    int row = imin(base + s * 16 + m, KE - 1);
    int es = eidx[row], ed = eidx[KE + row];
    const bf16x8* psrc = (const bf16x8*)(x2bf + es * 64);
    const bf16x8* pdst = (const bf16x8*)(x2bf + ed * 64);
    A[s][0] = psrc[q];
    A[s][1] = psrc[q + 4];
    A[s][2] = pdst[q];
    A[s][3] = pdst[q + 4];
  }
  // K-extension fragment: [ea0, ea1, 1, 0...] in lanes q==0
  bf16x8 A5[4];
#pragma unroll
  for (int s = 0; s < 4; ++s) {
    bf16x8 a5 = {0, 0, 0, 0, 0, 0, 0, 0};
    if (q == 0) {
      int row = imin(base + s * 16 + m, KE - 1);
      a5[0] = (__bf16)eattr[row * 2 + 0];
      a5[1] = (__bf16)eattr[row * 2 + 1];
      a5[2] = (__bf16)1.0f;
    }
    A5[s] = a5;
  }

  f32x2 osum[4][2];
#pragma unroll
  for (int s = 0; s < 4; ++s) {
    osum[s][0] = (f32x2){0.f, 0.f};
    osum[s][1] = (f32x2){0.f, 0.f};
  }

  const uint4* gB = (const uint4*)wm1t;  // chunk ch = uint4 [ch*1280, ch*1280+1280)
  // prologue: stage chunk 0
#pragma unroll
  for (int k = 0; k < 5; ++k) Bbuf[0][tid + k * 256] = gB[tid + k * 256];
  __syncthreads();

#pragma unroll 1
  for (int ch = 0; ch < 9; ++ch) {
    int cur = ch & 1, nxt = cur ^ 1;
    uint4 pf[5];
    if (ch < 8) {  // prefetch next chunk (consumed after compute)
      const uint4* gs = gB + (ch + 1) * 1280;
#pragma unroll
      for (int k = 0; k < 5; ++k) pf[k] = gs[tid + k * 256];
    }
#pragma unroll 1
    for (int li = 0; li < 4; ++li) {
      int nt = ch * 4 + li;
      if (nt > 32) break;  // wave-uniform
      const bf16x8* lb = (const bf16x8*)(Bbuf[cur] + li * 5 * 64);
      bf16x8 B0 = lb[0 * 64 + lane];
      bf16x8 B1 = lb[1 * 64 + lane];
      bf16x8 B2 = lb[2 * 64 + lane];
      bf16x8 B3 = lb[3 * 64 + lane];
      bf16x8 B4 = lb[4 * 64 + lane];
      float2 w2 = wsc2[nt * 64 + lane];
#pragma unroll
      for (int s = 0; s < 4; ++s) {
        f32x4 acc = {0.f, 0.f, 0.f, 0.f};
        acc = __builtin_amdgcn_mfma_f32_16x16x32_bf16(A[s][0], B0, acc, 0, 0, 0);
        acc = __builtin_amdgcn_mfma_f32_16x16x32_bf16(A[s][1], B1, acc, 0, 0, 0);
        acc = __builtin_amdgcn_mfma_f32_16x16x32_bf16(A[s][2], B2, acc, 0, 0, 0);
        acc = __builtin_amdgcn_mfma_f32_16x16x32_bf16(A[s][3], B3, acc, 0, 0, 0);
        acc = __builtin_amdgcn_mfma_f32_16x16x32_bf16(A5[s],   B4, acc, 0, 0, 0);
        f32x2 t0 = {fminf(acc[0], 0.f), fminf(acc[1], 0.f)};
        f32x2 t1 = {fminf(acc[2], 0.f), fminf(acc[3], 0.f)};
        f32x2 e0 = {fexp2(t0.x), fexp2(t0.y)};
        f32x2 e1 = {fexp2(t1.x), fexp2(t1.y)};
        osum[s][0] += e0 * w2.x + t0 * w2.y;  // pk_fma pairs
        osum[s][1] += e1 * w2.x + t1 * w2.y;
      }
    }
    if (ch < 8) {  // stage next chunk (load latency covered by compute)
#pragma unroll
      for (int k = 0; k < 5; ++k) Bbuf[nxt][tid + k * 256] = pf[k];
      __syncthreads();
    }
  }

  // linear composite tile (natural units): c_hi in col 0, c_lo in col 1
  const bf16x8* bt = (const bf16x8*)wm1t;
  bf16x8 L0 = bt[(33 * 5 + 0) * 64 + lane];
  bf16x8 L1 = bt[(33 * 5 + 1) * 64 + lane];
  bf16x8 L2 = bt[(33 * 5 + 2) * 64 + lane];
  bf16x8 L3 = bt[(33 * 5 + 3) * 64 + lane];
  bf16x8 L4 = bt[(33 * 5 + 4) * 64 + lane];
  float w2s = w2sum[0];
  float b2v = bm2[0];

#pragma unroll
  for (int s = 0; s < 4; ++s) {
    f32x4 accL = {0.f, 0.f, 0.f, 0.f};
    accL = __builtin_amdgcn_mfma_f32_16x16x32_bf16(A[s][0], L0, accL, 0, 0, 0);
    accL = __builtin_amdgcn_mfma_f32_16x16x32_bf16(A[s][1], L1, accL, 0, 0, 0);
    accL = __builtin_amdgcn_mfma_f32_16x16x32_bf16(A[s][2], L2, accL, 0, 0, 0);
    accL = __builtin_amdgcn_mfma_f32_16x16x32_bf16(A[s][3], L3, accL, 0, 0, 0);
    accL = __builtin_amdgcn_mfma_f32_16x16x32_bf16(A5[s],   L4, accL, 0, 0, 0);
    float ov[4] = {osum[s][0].x, osum[s][0].y, osum[s][1].x, osum[s][1].y};
#pragma unroll
    for (int r = 0; r < 4; ++r) {
      float lin = accL[r] + __shfl_xor(accL[r], 1);  // c_hi (m=0) + c_lo (m=1)
      float v = ov[r];
      v += __shfl_xor(v, 1);
      v += __shfl_xor(v, 2);
      v += __shfl_xor(v, 4);
      v += __shfl_xor(v, 8);
      if (m == 0) {
        int row = base + s * 16 + q * 4 + r;
        if (row < KE) out[row] = v - w2s + lin + b2v;
      }
    }
  }
}

extern "C" void kernel_launch(void* const* d_in, const int* in_sizes, int n_in,
                              void* d_out, int out_size, void* d_ws, size_t ws_size,
                              hipStream_t stream) {
  const float* pos  = (const float*)d_in[0];
  const int* eidx   = (const int*)d_in[1];
  const int* geidx  = (const int*)d_in[2];
  const float* eattr= (const float*)d_in[3];
  const float* W0   = (const float*)d_in[4];
  const float* as0  = (const float*)d_in[5];
  const float* ad0  = (const float*)d_in[6];
  const float* b0   = (const float*)d_in[7];
  const float* W1   = (const float*)d_in[8];
  const float* as1  = (const float*)d_in[9];
  const float* ad1  = (const float*)d_in[10];
  const float* b1   = (const float*)d_in[11];
  const float* Wm1  = (const float*)d_in[12];
  const float* bm1  = (const float*)d_in[13];
  const float* Wm2  = (const float*)d_in[14];
  const float* bm2  = (const float*)d_in[15];
  float* out = (float*)d_out;

  char* ws = (char*)d_ws;
  size_t off = 0;
  auto carve = [&](size_t bytes) {
    char* p = ws + off;
    off = (off + bytes + 255) & ~(size_t)255;
    return p;
  };
  int* counts    = (int*)carve((size_t)KN * 4);    // zeroed by memset below
  int* cursor    = (int*)carve((size_t)KN * 4);    // zeroed by memset below
  int* incl      = (int*)carve((size_t)KN * 4);
  int* row_start = (int*)carve((size_t)KN * 4);
  int* bsum      = (int*)carve(128 * 4);
  int* boff      = (int*)carve(128 * 4);
  int* csr_src   = (int*)carve((size_t)KEG * 4);
  int* csr_dst   = (int*)carve((size_t)KEG * 4);
  float* ew      = (float*)carve((size_t)KEG * 4);
  u16* h         = (u16*)carve((size_t)KN * 64 * 2);
  u16* x12       = (u16*)carve((size_t)KN * 64 * 2);
  float* a_s     = (float*)carve((size_t)KN * 4);
  float* a_d     = (float*)carve((size_t)KN * 4);
  u16* wm1t      = (u16*)carve((size_t)36 * 5 * 512 * 2);  // tiles 34..35 = pad
  u16* w1t       = (u16*)carve((size_t)4 * 2 * 64 * 8 * 2);
  float2* wsc2   = (float2*)carve((size_t)33 * 64 * 8);
  float* w2sum   = (float*)carve(256);

  const int* gsrc = geidx;
  const int* gdst = geidx + KEG;

  // zero counts+cursor (contiguous at ws start: 400128 + 400000 bytes)
  hipMemsetAsync(d_ws, 0, 800128, stream);

  // fused front: prep + cvec + hist + transform0
  k_front<<<FB_PREP + FB_CVEC + FB_HIST + FB_T0, 256, 0, stream>>>(
      pos, W0, as0, ad0, Wm1, bm1, Wm2, W1, gdst,
      wm1t, w1t, wsc2, w2sum, counts, h, a_s, a_d);

  k_scan_block<<<NB, 1024, 0, stream>>>(counts, incl, bsum);
  k_scan_bsum<<<1, 64, 0, stream>>>(bsum, boff);
  k_scan_final<<<NB, 1024, 0, stream>>>(incl, counts, boff, row_start);
  k_fill<<<(KEG + 255) / 256, 256, 0, stream>>>(gsrc, gdst, row_start, cursor,
                                                a_s, a_d, csr_src, csr_dst, ew);

  // ---- GAT layer 0 ----
  k_gat_agg<<<KN / 4, 256, 0, stream>>>(row_start, counts, csr_src, ew, h, b0, x12);

  // ---- GAT layer 1 ----
  k_transform1<<<(KN + 63) / 64, 256, 0, stream>>>(x12, w1t, as1, ad1, h, a_s, a_d);
  k_ew<<<(KEG + 255) / 256, 256, 0, stream>>>(csr_src, csr_dst, a_s, a_d, ew);
  k_gat_agg<<<KN / 4, 256, 0, stream>>>(row_start, counts, csr_src, ew, h, b1, x12);

  // ---- fused edge MLP (chunked LDS double-buffer, f32 out) ----
  k_edge_mlp<<<(KE + 255) / 256, 256, 0, stream>>>(eidx, x12, eattr, wm1t, wsc2, w2sum, bm2, out);
}

// Round 12
// 399.840 us; speedup vs baseline: 1.1234x; 1.1234x over previous
//
#include <hip/hip_runtime.h>

#define KN 100000
#define KEG 600000
#define KE 600000
#define NB 98  // ceil(KN/1024) scan blocks
#define LOG2E 1.4426950408889634f
#define LN2 0.6931471805599453f

// k_front block ranges
#define FB_PREP 391
#define FB_CVEC 33
#define FB_HIST 2344
#define FB_T0 25000

using u16 = unsigned short;
typedef __bf16 bf16x8 __attribute__((ext_vector_type(8)));
typedef float f32x4 __attribute__((ext_vector_type(4)));
typedef float f32x2 __attribute__((ext_vector_type(2)));

__device__ __forceinline__ float b2f(u16 u) { return __uint_as_float(((unsigned)u) << 16); }
__device__ __forceinline__ u16 f2b(float f) {
  unsigned u = __float_as_uint(f);
  u += 0x7FFF + ((u >> 16) & 1);  // round-to-nearest-even
  return (u16)(u >> 16);
}
__device__ __forceinline__ int imin(int a, int b) { return a < b ? a : b; }
__device__ __forceinline__ float fexp2(float x) {
#if __has_builtin(__builtin_amdgcn_exp2f)
  return __builtin_amdgcn_exp2f(x);
#else
  return __expf(x * LN2);
#endif
}

// async global->LDS 16B copy (no VGPR round-trip). LDS dest is wave-uniform
// base + lane*16; callers pass per-lane pointers laid out exactly that way.
__device__ __forceinline__ void gload_lds16(const void* g, void* l) {
  __builtin_amdgcn_global_load_lds(
      (const __attribute__((address_space(1))) unsigned int*)g,
      (__attribute__((address_space(3))) unsigned int*)l,
      16, 0, 0);
}

// ---------------- fused front: prep + cvec + hist + transform0 ----------------
// wm1t: 36 tiles x 5 frags x 512 (tiles 34..35 = staging pad, never computed).
// Tiles 0..32: Wm1 rows 0..127 (frags 0..3) and K-ext rows [w128,w129,bm1]
// (frag 4), ALL x LOG2E. Tile 33 (owned by cvec range): linear composite
// c=B160@wm2 natural units, c_hi col0 / c_lo col1.
__global__ __launch_bounds__(256) void k_front(
    const float* __restrict__ pos, const float* __restrict__ W0,
    const float* __restrict__ att_s, const float* __restrict__ att_d,
    const float* __restrict__ wm1, const float* __restrict__ bm1,
    const float* __restrict__ wm2, const float* __restrict__ w1,
    const int* __restrict__ gdst,
    u16* __restrict__ wm1t, u16* __restrict__ w1t, float2* __restrict__ wsc2,
    float* __restrict__ w2sum, int* __restrict__ counts,
    u16* __restrict__ h, float* __restrict__ a_s, float* __restrict__ a_d) {
  int bid = blockIdx.x;
  if (bid < FB_PREP) {
    int idx = bid * 256 + threadIdx.x;
    if (idx < 33 * 5 * 512) {  // tiles 0..32 only
      int j = idx & 7;
      int lane = (idx >> 3) & 63;
      int f = (idx >> 9) % 5;
      int nt = idx / (512 * 5);
      int n = nt * 16 + (lane & 15);
      float v = 0.f;
      if (n < 520) {
        if (f < 4) {
          int k = f * 32 + (lane >> 4) * 8 + j;
          v = wm1[k * 520 + n] * LOG2E;
        } else {
          int kk = (lane >> 4) * 8 + j;
          if (kk == 0) v = wm1[128 * 520 + n] * LOG2E;
          else if (kk == 1) v = wm1[129 * 520 + n] * LOG2E;
          else if (kk == 2) v = bm1[n] * LOG2E;
        }
      }
      wm1t[idx] = f2b(v);
    }
    if (idx < 33 * 64) {
      int lane = idx & 63, nt = idx >> 6;
      int col = nt * 16 + (lane & 15);
      float w2 = (col < 520) ? wm2[col] : 0.f;
      float2 p; p.x = w2; p.y = -LN2 * w2;
      wsc2[idx] = p;
    }
    if (idx < 4 * 2 * 64 * 8) {  // W1 -> MFMA B frags
      int j = idx & 7;
      int lane = (idx >> 3) & 63;
      int kt = (idx >> 9) & 1;
      int nt = idx >> 10;
      int n = nt * 16 + (lane & 15);
      int k = kt * 32 + (lane >> 4) * 8 + j;
      w1t[idx] = f2b(w1[k * 64 + n]);
    }
  } else if (bid < FB_PREP + FB_CVEC) {
    // cvec: c_k = sum_h B160[k][h]*wm2[h]; w = row index 0..130; w==131 -> w2sum
    int lane = threadIdx.x & 63;
    int w = (bid - FB_PREP) * 4 + (threadIdx.x >> 6);
    float x = 0.f;
    if (w <= 129) {
      const float* row = wm1 + (size_t)w * 520;
#pragma unroll
      for (int j = 0; j < 8; ++j) x += row[j * 64 + lane] * wm2[j * 64 + lane];
      if (lane < 8) x += row[512 + lane] * wm2[512 + lane];
    } else if (w == 130) {
#pragma unroll
      for (int j = 0; j < 8; ++j) x += bm1[j * 64 + lane] * wm2[j * 64 + lane];
      if (lane < 8) x += bm1[512 + lane] * wm2[512 + lane];
    } else if (w == 131) {
#pragma unroll
      for (int j = 0; j < 8; ++j) x += wm2[j * 64 + lane];
      if (lane < 8) x += wm2[512 + lane];
    }
    for (int off = 1; off < 64; off <<= 1) x += __shfl_xor(x, off);
    if (w <= 130 && lane < 16) {
      int f = w >> 5, kk = w & 31;
      int qq = kk >> 3, jj = kk & 7;
      u16 chi = f2b(x);
      float v = (lane == 0) ? x : (lane == 1 ? (x - b2f(chi)) : 0.f);
      wm1t[(33 * 5 + f) * 512 + (qq * 16 + lane) * 8 + jj] = f2b(v);
    } else if (w == 131 && lane == 0) {
      w2sum[0] = x;
    }
  } else if (bid < FB_PREP + FB_CVEC + FB_HIST) {
    int e = (bid - (FB_PREP + FB_CVEC)) * 256 + threadIdx.x;
    if (e < KEG) atomicAdd(counts + gdst[e], 1);
  } else {
    // transform0: h = pos @ W0, a_s/a_d reductions. 25000 blocks x 4 nodes.
    int lane = threadIdx.x & 63;
    int n = (bid - (FB_PREP + FB_CVEC + FB_HIST)) * 4 + (threadIdx.x >> 6);
    float p0 = pos[n * 3 + 0], p1 = pos[n * 3 + 1], p2 = pos[n * 3 + 2];
    float hv = p0 * W0[lane] + p1 * W0[64 + lane] + p2 * W0[128 + lane];
    h[n * 64 + lane] = f2b(hv);
    float s = hv * att_s[lane];
    float d = hv * att_d[lane];
    for (int off = 1; off < 64; off <<= 1) { s += __shfl_xor(s, off); d += __shfl_xor(d, off); }
    if (lane == 0) { a_s[n] = s; a_d[n] = d; }
  }
}

// ---------------- CSR build ----------------

__global__ __launch_bounds__(1024) void k_scan_block(
    const int* __restrict__ counts, int* __restrict__ incl, int* __restrict__ bsum) {
  int gid = blockIdx.x * 1024 + threadIdx.x;
  int lane = threadIdx.x & 63, w = threadIdx.x >> 6;
  int x = (gid < KN) ? counts[gid] : 0;
  for (int off = 1; off < 64; off <<= 1) {
    int y = __shfl_up(x, off);
    if (lane >= off) x += y;
  }
  __shared__ int wtot[16];
  if (lane == 63) wtot[w] = x;
  __syncthreads();
  if (w == 0 && lane < 16) {
    int t = wtot[lane];
    for (int off = 1; off < 16; off <<= 1) {
      int y = __shfl_up(t, off);
      if (lane >= off) t += y;
    }
    wtot[lane] = t;
  }
  __syncthreads();
  if (w > 0) x += wtot[w - 1];
  if (gid < KN) incl[gid] = x;
  if (threadIdx.x == 1023) bsum[blockIdx.x] = x;
}

__global__ __launch_bounds__(64) void k_scan_bsum(const int* __restrict__ bsum, int* __restrict__ boff) {
  int lane = threadIdx.x;
  int x0 = (lane < NB) ? bsum[lane] : 0;
  int x1 = (64 + lane < NB) ? bsum[64 + lane] : 0;
  int i0 = x0, i1 = x1;
  for (int off = 1; off < 64; off <<= 1) {
    int y0 = __shfl_up(i0, off), y1 = __shfl_up(i1, off);
    if (lane >= off) { i0 += y0; i1 += y1; }
  }
  int tot0 = __shfl(i0, 63);
  if (lane < NB) boff[lane] = i0 - x0;
  if (64 + lane < NB) boff[64 + lane] = i1 - x1 + tot0;
}

__global__ __launch_bounds__(1024) void k_scan_final(
    const int* __restrict__ incl, const int* __restrict__ counts,
    const int* __restrict__ boff, int* __restrict__ row_start) {
  int gid = blockIdx.x * 1024 + threadIdx.x;
  if (gid < KN) row_start[gid] = incl[gid] - counts[gid] + boff[blockIdx.x];
}

// fill CSR (src+dst) and layer-0 edge weights ew0=exp(leakyrelu(a_s+a_d))
__global__ __launch_bounds__(256) void k_fill(
    const int* __restrict__ gsrc, const int* __restrict__ gdst,
    const int* __restrict__ row_start, int* __restrict__ cursor,
    const float* __restrict__ a_s, const float* __restrict__ a_d,
    int* __restrict__ csr_src, int* __restrict__ csr_dst, float* __restrict__ ew) {
  int e = blockIdx.x * 256 + threadIdx.x;
  if (e >= KEG) return;
  int s = gsrc[e], d = gdst[e];
  int pos = atomicAdd(cursor + d, 1);
  int slot = row_start[d] + pos;
  csr_src[slot] = s;
  csr_dst[slot] = d;
  float al = a_s[s] + a_d[d];
  al = al > 0.f ? al : 0.2f * al;
  ew[slot] = __expf(al);
}

// layer-1 edge weights in CSR order
__global__ __launch_bounds__(256) void k_ew(
    const int* __restrict__ csr_src, const int* __restrict__ csr_dst,
    const float* __restrict__ a_s, const float* __restrict__ a_d, float* __restrict__ ew) {
  int slot = blockIdx.x * 256 + threadIdx.x;
  if (slot >= KEG) return;
  float al = a_s[csr_src[slot]] + a_d[csr_dst[slot]];
  al = al > 0.f ? al : 0.2f * al;
  ew[slot] = __expf(al);
}

// ---------------- GAT layers ----------------

// layer1 transform via MFMA: 16 nodes/wave, h = x @ W1 (64x64), fused a_s/a_d.
__global__ __launch_bounds__(256) void k_transform1(
    const u16* __restrict__ x, const u16* __restrict__ w1t,
    const float* __restrict__ att_s, const float* __restrict__ att_d,
    u16* __restrict__ h, float* __restrict__ a_s, float* __restrict__ a_d) {
  int lane = threadIdx.x & 63;
  int wave = threadIdx.x >> 6;
  int nodebase = blockIdx.x * 64 + wave * 16;
  int m = lane & 15, q = lane >> 4;

  int node = imin(nodebase + m, KN - 1);
  const bf16x8* px = (const bf16x8*)(x + node * 64);
  bf16x8 A0 = px[q];      // k 0..31
  bf16x8 A1 = px[q + 4];  // k 32..63

  const bf16x8* bt = (const bf16x8*)w1t;
  float ps[4] = {0.f, 0.f, 0.f, 0.f};
  float pd[4] = {0.f, 0.f, 0.f, 0.f};
#pragma unroll
  for (int nt = 0; nt < 4; ++nt) {
    int col = nt * 16 + m;
    float asv = att_s[col], adv = att_d[col];
    f32x4 acc = {0.f, 0.f, 0.f, 0.f};
    acc = __builtin_amdgcn_mfma_f32_16x16x32_bf16(A0, bt[(nt * 2 + 0) * 64 + lane], acc, 0, 0, 0);
    acc = __builtin_amdgcn_mfma_f32_16x16x32_bf16(A1, bt[(nt * 2 + 1) * 64 + lane], acc, 0, 0, 0);
#pragma unroll
    for (int r = 0; r < 4; ++r) {
      int rown = nodebase + q * 4 + r;
      if (rown < KN) h[rown * 64 + col] = f2b(acc[r]);
      ps[r] += acc[r] * asv;
      pd[r] += acc[r] * adv;
    }
  }
#pragma unroll
  for (int r = 0; r < 4; ++r) {
    float s = ps[r], d = pd[r];
    s += __shfl_xor(s, 1); d += __shfl_xor(d, 1);
    s += __shfl_xor(s, 2); d += __shfl_xor(d, 2);
    s += __shfl_xor(s, 4); d += __shfl_xor(d, 4);
    s += __shfl_xor(s, 8); d += __shfl_xor(d, 8);
    int rown = nodebase + q * 4 + r;
    if (m == 0 && rown < KN) { a_s[rown] = s; a_d[rown] = d; }
  }
}

// aggregate with precomputed weights: one wave per dst node, 4-way ILP unroll.
__global__ __launch_bounds__(256) void k_gat_agg(
    const int* __restrict__ row_start, const int* __restrict__ counts,
    const int* __restrict__ csr_src, const float* __restrict__ ew,
    const u16* __restrict__ h, const float* __restrict__ bias, u16* __restrict__ xout) {
  int lane = threadIdx.x & 63;
  int n = blockIdx.x * 4 + (threadIdx.x >> 6);  // grid covers KN exactly
  int start = row_start[n], deg = counts[n];
  float acc = 0.f, den = 0.f;
  int j = 0;
  for (; j + 4 <= deg; j += 4) {
    int s0 = csr_src[start + j];
    int s1 = csr_src[start + j + 1];
    int s2 = csr_src[start + j + 2];
    int s3 = csr_src[start + j + 3];
    float w0 = ew[start + j], w1 = ew[start + j + 1];
    float w2 = ew[start + j + 2], w3 = ew[start + j + 3];
    float h0 = b2f(h[s0 * 64 + lane]);
    float h1 = b2f(h[s1 * 64 + lane]);
    float h2 = b2f(h[s2 * 64 + lane]);
    float h3 = b2f(h[s3 * 64 + lane]);
    den += (w0 + w1) + (w2 + w3);
    acc += w0 * h0 + w1 * h1 + w2 * h2 + w3 * h3;
  }
  for (; j < deg; ++j) {
    int s0 = csr_src[start + j];
    float w0 = ew[start + j];
    den += w0;
    acc += w0 * b2f(h[s0 * 64 + lane]);
  }
  float v = acc / (den + 1e-16f) + bias[lane];
  v = v > 0.f ? v : expm1f(v);
  xout[n * 64 + lane] = f2b(v);
}

// ---------------- edge MLP ----------------
// Chunked LDS double-buffer staged via async global_load_lds (no VGPR round
// trip, nothing to spill): per chunk issue 5x16B direct-to-LDS loads for
// chunk+1, compute 4 nt-tiles from the current buffer, then one barrier
// (drains vmcnt -> next buffer ready). 9 barriers total. Per element:
// t=min(acc2,0); e=exp2(t); osum += e*w2 + t*(-ln2*w2). Linear part via the
// precomputed composite tile 33 (c_hi col0 + c_lo col1).
__global__ __launch_bounds__(256) void k_edge_mlp(
    const int* __restrict__ eidx, const u16* __restrict__ x2bf,
    const float* __restrict__ eattr, const u16* __restrict__ wm1t,
    const float2* __restrict__ wsc2, const float* __restrict__ w2sum,
    const float* __restrict__ bm2, float* __restrict__ out) {
  __shared__ uint4 Bbuf[2][20 * 64];  // 40 KB
  int tid = threadIdx.x;
  int lane = tid & 63;
  int wave = tid >> 6;
  int base = blockIdx.x * 256 + wave * 64;
  int m = lane & 15, q = lane >> 4;

  const uint4* gB = (const uint4*)wm1t;  // chunk ch = uint4 [ch*1280, +1280)
  // prologue: async-stage chunk 0 (lds dest = wave-uniform base + lane*16)
#pragma unroll
  for (int k = 0; k < 5; ++k)
    gload_lds16(gB + tid + k * 256, &Bbuf[0][tid + k * 256]);

  // A fragments: A[m=lane&15][k=q*8+j]
  bf16x8 A[4][4];
#pragma unroll
  for (int s = 0; s < 4; ++s) {
    int row = imin(base + s * 16 + m, KE - 1);
    int es = eidx[row], ed = eidx[KE + row];
    const bf16x8* psrc = (const bf16x8*)(x2bf + es * 64);
    const bf16x8* pdst = (const bf16x8*)(x2bf + ed * 64);
    A[s][0] = psrc[q];
    A[s][1] = psrc[q + 4];
    A[s][2] = pdst[q];
    A[s][3] = pdst[q + 4];
  }
  // K-extension fragment: [ea0, ea1, 1, 0...] in lanes q==0
  bf16x8 A5[4];
#pragma unroll
  for (int s = 0; s < 4; ++s) {
    bf16x8 a5 = {0, 0, 0, 0, 0, 0, 0, 0};
    if (q == 0) {
      int row = imin(base + s * 16 + m, KE - 1);
      a5[0] = (__bf16)eattr[row * 2 + 0];
      a5[1] = (__bf16)eattr[row * 2 + 1];
      a5[2] = (__bf16)1.0f;
    }
    A5[s] = a5;
  }

  f32x2 osum[4][2];
#pragma unroll
  for (int s = 0; s < 4; ++s) {
    osum[s][0] = (f32x2){0.f, 0.f};
    osum[s][1] = (f32x2){0.f, 0.f};
  }

  __syncthreads();  // chunk 0 landed (vmcnt drained by barrier semantics)

#pragma unroll 1
  for (int ch = 0; ch < 9; ++ch) {
    int cur = ch & 1, nxt = cur ^ 1;
    if (ch < 8) {  // async prefetch of chunk ch+1 into the other buffer
      const uint4* gs = gB + (ch + 1) * 1280;
#pragma unroll
      for (int k = 0; k < 5; ++k)
        gload_lds16(gs + tid + k * 256, &Bbuf[nxt][tid + k * 256]);
    }
    int lim = (ch == 8) ? 1 : 4;  // tiles 0..32 computed; 33..35 staged only
#pragma unroll 1
    for (int li = 0; li < lim; ++li) {
      int nt = ch * 4 + li;
      const bf16x8* lb = (const bf16x8*)(Bbuf[cur] + li * 5 * 64);
      bf16x8 B0 = lb[0 * 64 + lane];
      bf16x8 B1 = lb[1 * 64 + lane];
      bf16x8 B2 = lb[2 * 64 + lane];
      bf16x8 B3 = lb[3 * 64 + lane];
      bf16x8 B4 = lb[4 * 64 + lane];
      float2 w2 = wsc2[nt * 64 + lane];
#pragma unroll
      for (int s = 0; s < 4; ++s) {
        f32x4 acc = {0.f, 0.f, 0.f, 0.f};
        acc = __builtin_amdgcn_mfma_f32_16x16x32_bf16(A[s][0], B0, acc, 0, 0, 0);
        acc = __builtin_amdgcn_mfma_f32_16x16x32_bf16(A[s][1], B1, acc, 0, 0, 0);
        acc = __builtin_amdgcn_mfma_f32_16x16x32_bf16(A[s][2], B2, acc, 0, 0, 0);
        acc = __builtin_amdgcn_mfma_f32_16x16x32_bf16(A[s][3], B3, acc, 0, 0, 0);
        acc = __builtin_amdgcn_mfma_f32_16x16x32_bf16(A5[s],   B4, acc, 0, 0, 0);
        f32x2 t0 = {fminf(acc[0], 0.f), fminf(acc[1], 0.f)};
        f32x2 t1 = {fminf(acc[2], 0.f), fminf(acc[3], 0.f)};
        f32x2 e0 = {fexp2(t0.x), fexp2(t0.y)};
        f32x2 e1 = {fexp2(t1.x), fexp2(t1.y)};
        osum[s][0] += e0 * w2.x + t0 * w2.y;  // pk_fma pairs
        osum[s][1] += e1 * w2.x + t1 * w2.y;
      }
    }
    if (ch < 8) __syncthreads();  // drains async loads; buffer swap safe
  }

  // linear composite tile (natural units): c_hi in col 0, c_lo in col 1
  const bf16x8* bt = (const bf16x8*)wm1t;
  bf16x8 L0 = bt[(33 * 5 + 0) * 64 + lane];
  bf16x8 L1 = bt[(33 * 5 + 1) * 64 + lane];
  bf16x8 L2 = bt[(33 * 5 + 2) * 64 + lane];
  bf16x8 L3 = bt[(33 * 5 + 3) * 64 + lane];
  bf16x8 L4 = bt[(33 * 5 + 4) * 64 + lane];
  float w2s = w2sum[0];
  float b2v = bm2[0];

#pragma unroll
  for (int s = 0; s < 4; ++s) {
    f32x4 accL = {0.f, 0.f, 0.f, 0.f};
    accL = __builtin_amdgcn_mfma_f32_16x16x32_bf16(A[s][0], L0, accL, 0, 0, 0);
    accL = __builtin_amdgcn_mfma_f32_16x16x32_bf16(A[s][1], L1, accL, 0, 0, 0);
    accL = __builtin_amdgcn_mfma_f32_16x16x32_bf16(A[s][2], L2, accL, 0, 0, 0);
    accL = __builtin_amdgcn_mfma_f32_16x16x32_bf16(A[s][3], L3, accL, 0, 0, 0);
    accL = __builtin_amdgcn_mfma_f32_16x16x32_bf16(A5[s],   L4, accL, 0, 0, 0);
    float ov[4] = {osum[s][0].x, osum[s][0].y, osum[s][1].x, osum[s][1].y};
#pragma unroll
    for (int r = 0; r < 4; ++r) {
      float lin = accL[r] + __shfl_xor(accL[r], 1);  // c_hi (m=0) + c_lo (m=1)
      float v = ov[r];
      v += __shfl_xor(v, 1);
      v += __shfl_xor(v, 2);
      v += __shfl_xor(v, 4);
      v += __shfl_xor(v, 8);
      if (m == 0) {
        int row = base + s * 16 + q * 4 + r;
        if (row < KE) out[row] = v - w2s + lin + b2v;
      }
    }
  }
}

extern "C" void kernel_launch(void* const* d_in, const int* in_sizes, int n_in,
                              void* d_out, int out_size, void* d_ws, size_t ws_size,
                              hipStream_t stream) {
  const float* pos  = (const float*)d_in[0];
  const int* eidx   = (const int*)d_in[1];
  const int* geidx  = (const int*)d_in[2];
  const float* eattr= (const float*)d_in[3];
  const float* W0   = (const float*)d_in[4];
  const float* as0  = (const float*)d_in[5];
  const float* ad0  = (const float*)d_in[6];
  const float* b0   = (const float*)d_in[7];
  const float* W1   = (const float*)d_in[8];
  const float* as1  = (const float*)d_in[9];
  const float* ad1  = (const float*)d_in[10];
  const float* b1   = (const float*)d_in[11];
  const float* Wm1  = (const float*)d_in[12];
  const float* bm1  = (const float*)d_in[13];
  const float* Wm2  = (const float*)d_in[14];
  const float* bm2  = (const float*)d_in[15];
  float* out = (float*)d_out;

  char* ws = (char*)d_ws;
  size_t off = 0;
  auto carve = [&](size_t bytes) {
    char* p = ws + off;
    off = (off + bytes + 255) & ~(size_t)255;
    return p;
  };
  int* counts    = (int*)carve((size_t)KN * 4);    // zeroed by memset below
  int* cursor    = (int*)carve((size_t)KN * 4);    // zeroed by memset below
  int* incl      = (int*)carve((size_t)KN * 4);
  int* row_start = (int*)carve((size_t)KN * 4);
  int* bsum      = (int*)carve(128 * 4);
  int* boff      = (int*)carve(128 * 4);
  int* csr_src   = (int*)carve((size_t)KEG * 4);
  int* csr_dst   = (int*)carve((size_t)KEG * 4);
  float* ew      = (float*)carve((size_t)KEG * 4);
  u16* h         = (u16*)carve((size_t)KN * 64 * 2);
  u16* x12       = (u16*)carve((size_t)KN * 64 * 2);
  float* a_s     = (float*)carve((size_t)KN * 4);
  float* a_d     = (float*)carve((size_t)KN * 4);
  u16* wm1t      = (u16*)carve((size_t)36 * 5 * 512 * 2);  // tiles 34..35 = pad
  u16* w1t       = (u16*)carve((size_t)4 * 2 * 64 * 8 * 2);
  float2* wsc2   = (float2*)carve((size_t)33 * 64 * 8);
  float* w2sum   = (float*)carve(256);

  const int* gsrc = geidx;
  const int* gdst = geidx + KEG;

  // zero counts+cursor (contiguous at ws start: 400128 + 400000 bytes)
  hipMemsetAsync(d_ws, 0, 800128, stream);

  // fused front: prep + cvec + hist + transform0
  k_front<<<FB_PREP + FB_CVEC + FB_HIST + FB_T0, 256, 0, stream>>>(
      pos, W0, as0, ad0, Wm1, bm1, Wm2, W1, gdst,
      wm1t, w1t, wsc2, w2sum, counts, h, a_s, a_d);

  k_scan_block<<<NB, 1024, 0, stream>>>(counts, incl, bsum);
  k_scan_bsum<<<1, 64, 0, stream>>>(bsum, boff);
  k_scan_final<<<NB, 1024, 0, stream>>>(incl, counts, boff, row_start);
  k_fill<<<(KEG + 255) / 256, 256, 0, stream>>>(gsrc, gdst, row_start, cursor,
                                                a_s, a_d, csr_src, csr_dst, ew);

  // ---- GAT layer 0 ----
  k_gat_agg<<<KN / 4, 256, 0, stream>>>(row_start, counts, csr_src, ew, h, b0, x12);

  // ---- GAT layer 1 ----
  k_transform1<<<(KN + 63) / 64, 256, 0, stream>>>(x12, w1t, as1, ad1, h, a_s, a_d);
  k_ew<<<(KEG + 255) / 256, 256, 0, stream>>>(csr_src, csr_dst, a_s, a_d, ew);
  k_gat_agg<<<KN / 4, 256, 0, stream>>>(row_start, counts, csr_src, ew, h, b1, x12);

  // ---- fused edge MLP (async-LDS chunked double-buffer, f32 out) ----
  k_edge_mlp<<<(KE + 255) / 256, 256, 0, stream>>>(eidx, x12, eattr, wm1t, wsc2, w2sum, bm2, out);
}

// Round 13
// 390.808 us; speedup vs baseline: 1.1493x; 1.0231x over previous
//
#include <hip/hip_runtime.h>

#define KN 100000
#define KEG 600000
#define KE 600000
#define NB 98  // ceil(KN/1024) scan blocks
#define LOG2E 1.4426950408889634f
#define LN2 0.6931471805599453f

// k_front block ranges
#define FB_PREP 391
#define FB_CVEC 33
#define FB_HIST 2344
#define FB_T0 25000

using u16 = unsigned short;
typedef __bf16 bf16x8 __attribute__((ext_vector_type(8)));
typedef float f32x4 __attribute__((ext_vector_type(4)));
typedef float f32x2 __attribute__((ext_vector_type(2)));

__device__ __forceinline__ float b2f(u16 u) { return __uint_as_float(((unsigned)u) << 16); }
__device__ __forceinline__ u16 f2b(float f) {
  unsigned u = __float_as_uint(f);
  u += 0x7FFF + ((u >> 16) & 1);  // round-to-nearest-even
  return (u16)(u >> 16);
}
__device__ __forceinline__ int imin(int a, int b) { return a < b ? a : b; }
__device__ __forceinline__ float fexp2(float x) {
#if __has_builtin(__builtin_amdgcn_exp2f)
  return __builtin_amdgcn_exp2f(x);
#else
  return __expf(x * LN2);
#endif
}

// async global->LDS 16B copy (no VGPR round-trip). LDS dest is wave-uniform
// base + lane*16; callers pass per-lane pointers laid out exactly that way.
__device__ __forceinline__ void gload_lds16(const void* g, void* l) {
  __builtin_amdgcn_global_load_lds(
      (const __attribute__((address_space(1))) unsigned int*)g,
      (__attribute__((address_space(3))) unsigned int*)l,
      16, 0, 0);
}

// ---------------- fused front: prep + cvec + hist + transform0 ----------------
// wm1t: 36 tiles x 5 frags x 512 (tiles 34..35 = staging pad, never computed).
// Tiles 0..32: Wm1 rows 0..127 (frags 0..3) and K-ext rows [w128,w129,bm1]
// (frag 4), ALL x LOG2E. Tile 33 (owned by cvec range): linear composite
// c=B160@wm2 natural units, c_hi col0 / c_lo col1.
__global__ __launch_bounds__(256) void k_front(
    const float* __restrict__ pos, const float* __restrict__ W0,
    const float* __restrict__ att_s, const float* __restrict__ att_d,
    const float* __restrict__ wm1, const float* __restrict__ bm1,
    const float* __restrict__ wm2, const float* __restrict__ w1,
    const int* __restrict__ gdst,
    u16* __restrict__ wm1t, u16* __restrict__ w1t, float2* __restrict__ wsc2,
    float* __restrict__ w2sum, int* __restrict__ counts,
    u16* __restrict__ h, float* __restrict__ a_s, float* __restrict__ a_d) {
  int bid = blockIdx.x;
  if (bid < FB_PREP) {
    int idx = bid * 256 + threadIdx.x;
    if (idx < 33 * 5 * 512) {  // tiles 0..32 only
      int j = idx & 7;
      int lane = (idx >> 3) & 63;
      int f = (idx >> 9) % 5;
      int nt = idx / (512 * 5);
      int n = nt * 16 + (lane & 15);
      float v = 0.f;
      if (n < 520) {
        if (f < 4) {
          int k = f * 32 + (lane >> 4) * 8 + j;
          v = wm1[k * 520 + n] * LOG2E;
        } else {
          int kk = (lane >> 4) * 8 + j;
          if (kk == 0) v = wm1[128 * 520 + n] * LOG2E;
          else if (kk == 1) v = wm1[129 * 520 + n] * LOG2E;
          else if (kk == 2) v = bm1[n] * LOG2E;
        }
      }
      wm1t[idx] = f2b(v);
    }
    if (idx < 33 * 64) {
      int lane = idx & 63, nt = idx >> 6;
      int col = nt * 16 + (lane & 15);
      float w2 = (col < 520) ? wm2[col] : 0.f;
      float2 p; p.x = w2; p.y = -LN2 * w2;
      wsc2[idx] = p;
    }
    if (idx < 4 * 2 * 64 * 8) {  // W1 -> MFMA B frags
      int j = idx & 7;
      int lane = (idx >> 3) & 63;
      int kt = (idx >> 9) & 1;
      int nt = idx >> 10;
      int n = nt * 16 + (lane & 15);
      int k = kt * 32 + (lane >> 4) * 8 + j;
      w1t[idx] = f2b(w1[k * 64 + n]);
    }
  } else if (bid < FB_PREP + FB_CVEC) {
    // cvec: c_k = sum_h B160[k][h]*wm2[h]; w = row index 0..130; w==131 -> w2sum
    int lane = threadIdx.x & 63;
    int w = (bid - FB_PREP) * 4 + (threadIdx.x >> 6);
    float x = 0.f;
    if (w <= 129) {
      const float* row = wm1 + (size_t)w * 520;
#pragma unroll
      for (int j = 0; j < 8; ++j) x += row[j * 64 + lane] * wm2[j * 64 + lane];
      if (lane < 8) x += row[512 + lane] * wm2[512 + lane];
    } else if (w == 130) {
#pragma unroll
      for (int j = 0; j < 8; ++j) x += bm1[j * 64 + lane] * wm2[j * 64 + lane];
      if (lane < 8) x += bm1[512 + lane] * wm2[512 + lane];
    } else if (w == 131) {
#pragma unroll
      for (int j = 0; j < 8; ++j) x += wm2[j * 64 + lane];
      if (lane < 8) x += wm2[512 + lane];
    }
    for (int off = 1; off < 64; off <<= 1) x += __shfl_xor(x, off);
    if (w <= 130 && lane < 16) {
      int f = w >> 5, kk = w & 31;
      int qq = kk >> 3, jj = kk & 7;
      u16 chi = f2b(x);
      float v = (lane == 0) ? x : (lane == 1 ? (x - b2f(chi)) : 0.f);
      wm1t[(33 * 5 + f) * 512 + (qq * 16 + lane) * 8 + jj] = f2b(v);
    } else if (w == 131 && lane == 0) {
      w2sum[0] = x;
    }
  } else if (bid < FB_PREP + FB_CVEC + FB_HIST) {
    int e = (bid - (FB_PREP + FB_CVEC)) * 256 + threadIdx.x;
    if (e < KEG) atomicAdd(counts + gdst[e], 1);
  } else {
    // transform0: h = pos @ W0, a_s/a_d reductions. 25000 blocks x 4 nodes.
    int lane = threadIdx.x & 63;
    int n = (bid - (FB_PREP + FB_CVEC + FB_HIST)) * 4 + (threadIdx.x >> 6);
    float p0 = pos[n * 3 + 0], p1 = pos[n * 3 + 1], p2 = pos[n * 3 + 2];
    float hv = p0 * W0[lane] + p1 * W0[64 + lane] + p2 * W0[128 + lane];
    h[n * 64 + lane] = f2b(hv);
    float s = hv * att_s[lane];
    float d = hv * att_d[lane];
    for (int off = 1; off < 64; off <<= 1) { s += __shfl_xor(s, off); d += __shfl_xor(d, off); }
    if (lane == 0) { a_s[n] = s; a_d[n] = d; }
  }
}

// ---------------- CSR build ----------------

__global__ __launch_bounds__(1024) void k_scan_block(
    const int* __restrict__ counts, int* __restrict__ incl, int* __restrict__ bsum) {
  int gid = blockIdx.x * 1024 + threadIdx.x;
  int lane = threadIdx.x & 63, w = threadIdx.x >> 6;
  int x = (gid < KN) ? counts[gid] : 0;
  for (int off = 1; off < 64; off <<= 1) {
    int y = __shfl_up(x, off);
    if (lane >= off) x += y;
  }
  __shared__ int wtot[16];
  if (lane == 63) wtot[w] = x;
  __syncthreads();
  if (w == 0 && lane < 16) {
    int t = wtot[lane];
    for (int off = 1; off < 16; off <<= 1) {
      int y = __shfl_up(t, off);
      if (lane >= off) t += y;
    }
    wtot[lane] = t;
  }
  __syncthreads();
  if (w > 0) x += wtot[w - 1];
  if (gid < KN) incl[gid] = x;
  if (threadIdx.x == 1023) bsum[blockIdx.x] = x;
}

__global__ __launch_bounds__(64) void k_scan_bsum(const int* __restrict__ bsum, int* __restrict__ boff) {
  int lane = threadIdx.x;
  int x0 = (lane < NB) ? bsum[lane] : 0;
  int x1 = (64 + lane < NB) ? bsum[64 + lane] : 0;
  int i0 = x0, i1 = x1;
  for (int off = 1; off < 64; off <<= 1) {
    int y0 = __shfl_up(i0, off), y1 = __shfl_up(i1, off);
    if (lane >= off) { i0 += y0; i1 += y1; }
  }
  int tot0 = __shfl(i0, 63);
  if (lane < NB) boff[lane] = i0 - x0;
  if (64 + lane < NB) boff[64 + lane] = i1 - x1 + tot0;
}

__global__ __launch_bounds__(1024) void k_scan_final(
    const int* __restrict__ incl, const int* __restrict__ counts,
    const int* __restrict__ boff, int* __restrict__ row_start) {
  int gid = blockIdx.x * 1024 + threadIdx.x;
  if (gid < KN) row_start[gid] = incl[gid] - counts[gid] + boff[blockIdx.x];
}

// fill CSR: one atomic + ONE scattered 4B store per edge (csr_dst/ew eliminated
// -- edge weights are recomputed inline in k_gat_agg where dst is implicit).
__global__ __launch_bounds__(256) void k_fill(
    const int* __restrict__ gsrc, const int* __restrict__ gdst,
    const int* __restrict__ row_start, int* __restrict__ cursor,
    int* __restrict__ csr_src) {
  int e = blockIdx.x * 256 + threadIdx.x;
  if (e >= KEG) return;
  int d = gdst[e];
  int pos = atomicAdd(cursor + d, 1);
  csr_src[row_start[d] + pos] = gsrc[e];
}

// ---------------- GAT layers ----------------

// layer1 transform via MFMA: 16 nodes/wave, h = x @ W1 (64x64), fused a_s/a_d.
__global__ __launch_bounds__(256) void k_transform1(
    const u16* __restrict__ x, const u16* __restrict__ w1t,
    const float* __restrict__ att_s, const float* __restrict__ att_d,
    u16* __restrict__ h, float* __restrict__ a_s, float* __restrict__ a_d) {
  int lane = threadIdx.x & 63;
  int wave = threadIdx.x >> 6;
  int nodebase = blockIdx.x * 64 + wave * 16;
  int m = lane & 15, q = lane >> 4;

  int node = imin(nodebase + m, KN - 1);
  const bf16x8* px = (const bf16x8*)(x + node * 64);
  bf16x8 A0 = px[q];      // k 0..31
  bf16x8 A1 = px[q + 4];  // k 32..63

  const bf16x8* bt = (const bf16x8*)w1t;
  float ps[4] = {0.f, 0.f, 0.f, 0.f};
  float pd[4] = {0.f, 0.f, 0.f, 0.f};
#pragma unroll
  for (int nt = 0; nt < 4; ++nt) {
    int col = nt * 16 + m;
    float asv = att_s[col], adv = att_d[col];
    f32x4 acc = {0.f, 0.f, 0.f, 0.f};
    acc = __builtin_amdgcn_mfma_f32_16x16x32_bf16(A0, bt[(nt * 2 + 0) * 64 + lane], acc, 0, 0, 0);
    acc = __builtin_amdgcn_mfma_f32_16x16x32_bf16(A1, bt[(nt * 2 + 1) * 64 + lane], acc, 0, 0, 0);
#pragma unroll
    for (int r = 0; r < 4; ++r) {
      int rown = nodebase + q * 4 + r;
      if (rown < KN) h[rown * 64 + col] = f2b(acc[r]);
      ps[r] += acc[r] * asv;
      pd[r] += acc[r] * adv;
    }
  }
#pragma unroll
  for (int r = 0; r < 4; ++r) {
    float s = ps[r], d = pd[r];
    s += __shfl_xor(s, 1); d += __shfl_xor(d, 1);
    s += __shfl_xor(s, 2); d += __shfl_xor(d, 2);
    s += __shfl_xor(s, 4); d += __shfl_xor(d, 4);
    s += __shfl_xor(s, 8); d += __shfl_xor(d, 8);
    int rown = nodebase + q * 4 + r;
    if (m == 0 && rown < KN) { a_s[rown] = s; a_d[rown] = d; }
  }
}

// fused softmax-weight + aggregate + bias + ELU: one wave per dst node,
// weights computed inline (a_d[n] wave-uniform, a_s gather L2-resident),
// 4-way ILP unroll keeps 4 independent gather chains in flight.
__global__ __launch_bounds__(256) void k_gat_agg(
    const int* __restrict__ row_start, const int* __restrict__ counts,
    const int* __restrict__ csr_src, const float* __restrict__ a_s,
    const float* __restrict__ a_d, const u16* __restrict__ h,
    const float* __restrict__ bias, u16* __restrict__ xout) {
  int lane = threadIdx.x & 63;
  int n = blockIdx.x * 4 + (threadIdx.x >> 6);  // grid covers KN exactly
  int start = row_start[n], deg = counts[n];
  float adn = a_d[n];
  float acc = 0.f, den = 0.f;
  int j = 0;
  for (; j + 4 <= deg; j += 4) {
    int s0 = csr_src[start + j];
    int s1 = csr_src[start + j + 1];
    int s2 = csr_src[start + j + 2];
    int s3 = csr_src[start + j + 3];
    float al0 = a_s[s0] + adn; al0 = al0 > 0.f ? al0 : 0.2f * al0;
    float al1 = a_s[s1] + adn; al1 = al1 > 0.f ? al1 : 0.2f * al1;
    float al2 = a_s[s2] + adn; al2 = al2 > 0.f ? al2 : 0.2f * al2;
    float al3 = a_s[s3] + adn; al3 = al3 > 0.f ? al3 : 0.2f * al3;
    float w0 = __expf(al0), w1 = __expf(al1);
    float w2 = __expf(al2), w3 = __expf(al3);
    float h0 = b2f(h[s0 * 64 + lane]);
    float h1 = b2f(h[s1 * 64 + lane]);
    float h2 = b2f(h[s2 * 64 + lane]);
    float h3 = b2f(h[s3 * 64 + lane]);
    den += (w0 + w1) + (w2 + w3);
    acc += w0 * h0 + w1 * h1 + w2 * h2 + w3 * h3;
  }
  for (; j < deg; ++j) {
    int s0 = csr_src[start + j];
    float al = a_s[s0] + adn; al = al > 0.f ? al : 0.2f * al;
    float w0 = __expf(al);
    den += w0;
    acc += w0 * b2f(h[s0 * 64 + lane]);
  }
  float v = acc / (den + 1e-16f) + bias[lane];
  v = v > 0.f ? v : expm1f(v);
  xout[n * 64 + lane] = f2b(v);
}

// ---------------- edge MLP ----------------
// Chunked LDS double-buffer staged via async global_load_lds (R12, unchanged):
// per chunk issue 5x16B direct-to-LDS loads for chunk+1, compute 4 nt-tiles,
// one barrier. Per element: t=min(acc2,0); e=exp2(t); osum += e*w2+t*(-ln2*w2).
// Linear part via composite tile 33 (c_hi col0 + c_lo col1).
__global__ __launch_bounds__(256) void k_edge_mlp(
    const int* __restrict__ eidx, const u16* __restrict__ x2bf,
    const float* __restrict__ eattr, const u16* __restrict__ wm1t,
    const float2* __restrict__ wsc2, const float* __restrict__ w2sum,
    const float* __restrict__ bm2, float* __restrict__ out) {
  __shared__ uint4 Bbuf[2][20 * 64];  // 40 KB
  int tid = threadIdx.x;
  int lane = tid & 63;
  int wave = tid >> 6;
  int base = blockIdx.x * 256 + wave * 64;
  int m = lane & 15, q = lane >> 4;

  const uint4* gB = (const uint4*)wm1t;  // chunk ch = uint4 [ch*1280, +1280)
  // prologue: async-stage chunk 0 (lds dest = wave-uniform base + lane*16)
#pragma unroll
  for (int k = 0; k < 5; ++k)
    gload_lds16(gB + tid + k * 256, &Bbuf[0][tid + k * 256]);

  // A fragments: A[m=lane&15][k=q*8+j]
  bf16x8 A[4][4];
#pragma unroll
  for (int s = 0; s < 4; ++s) {
    int row = imin(base + s * 16 + m, KE - 1);
    int es = eidx[row], ed = eidx[KE + row];
    const bf16x8* psrc = (const bf16x8*)(x2bf + es * 64);
    const bf16x8* pdst = (const bf16x8*)(x2bf + ed * 64);
    A[s][0] = psrc[q];
    A[s][1] = psrc[q + 4];
    A[s][2] = pdst[q];
    A[s][3] = pdst[q + 4];
  }
  // K-extension fragment: [ea0, ea1, 1, 0...] in lanes q==0
  bf16x8 A5[4];
#pragma unroll
  for (int s = 0; s < 4; ++s) {
    bf16x8 a5 = {0, 0, 0, 0, 0, 0, 0, 0};
    if (q == 0) {
      int row = imin(base + s * 16 + m, KE - 1);
      a5[0] = (__bf16)eattr[row * 2 + 0];
      a5[1] = (__bf16)eattr[row * 2 + 1];
      a5[2] = (__bf16)1.0f;
    }
    A5[s] = a5;
  }

  f32x2 osum[4][2];
#pragma unroll
  for (int s = 0; s < 4; ++s) {
    osum[s][0] = (f32x2){0.f, 0.f};
    osum[s][1] = (f32x2){0.f, 0.f};
  }

  __syncthreads();  // chunk 0 landed (vmcnt drained by barrier semantics)

#pragma unroll 1
  for (int ch = 0; ch < 9; ++ch) {
    int cur = ch & 1, nxt = cur ^ 1;
    if (ch < 8) {  // async prefetch of chunk ch+1 into the other buffer
      const uint4* gs = gB + (ch + 1) * 1280;
#pragma unroll
      for (int k = 0; k < 5; ++k)
        gload_lds16(gs + tid + k * 256, &Bbuf[nxt][tid + k * 256]);
    }
    int lim = (ch == 8) ? 1 : 4;  // tiles 0..32 computed; 33..35 staged only
#pragma unroll 1
    for (int li = 0; li < lim; ++li) {
      int nt = ch * 4 + li;
      const bf16x8* lb = (const bf16x8*)(Bbuf[cur] + li * 5 * 64);
      bf16x8 B0 = lb[0 * 64 + lane];
      bf16x8 B1 = lb[1 * 64 + lane];
      bf16x8 B2 = lb[2 * 64 + lane];
      bf16x8 B3 = lb[3 * 64 + lane];
      bf16x8 B4 = lb[4 * 64 + lane];
      float2 w2 = wsc2[nt * 64 + lane];
#pragma unroll
      for (int s = 0; s < 4; ++s) {
        f32x4 acc = {0.f, 0.f, 0.f, 0.f};
        acc = __builtin_amdgcn_mfma_f32_16x16x32_bf16(A[s][0], B0, acc, 0, 0, 0);
        acc = __builtin_amdgcn_mfma_f32_16x16x32_bf16(A[s][1], B1, acc, 0, 0, 0);
        acc = __builtin_amdgcn_mfma_f32_16x16x32_bf16(A[s][2], B2, acc, 0, 0, 0);
        acc = __builtin_amdgcn_mfma_f32_16x16x32_bf16(A[s][3], B3, acc, 0, 0, 0);
        acc = __builtin_amdgcn_mfma_f32_16x16x32_bf16(A5[s],   B4, acc, 0, 0, 0);
        f32x2 t0 = {fminf(acc[0], 0.f), fminf(acc[1], 0.f)};
        f32x2 t1 = {fminf(acc[2], 0.f), fminf(acc[3], 0.f)};
        f32x2 e0 = {fexp2(t0.x), fexp2(t0.y)};
        f32x2 e1 = {fexp2(t1.x), fexp2(t1.y)};
        osum[s][0] += e0 * w2.x + t0 * w2.y;  // pk_fma pairs
        osum[s][1] += e1 * w2.x + t1 * w2.y;
      }
    }
    if (ch < 8) __syncthreads();  // drains async loads; buffer swap safe
  }

  // linear composite tile (natural units): c_hi in col 0, c_lo in col 1
  const bf16x8* bt = (const bf16x8*)wm1t;
  bf16x8 L0 = bt[(33 * 5 + 0) * 64 + lane];
  bf16x8 L1 = bt[(33 * 5 + 1) * 64 + lane];
  bf16x8 L2 = bt[(33 * 5 + 2) * 64 + lane];
  bf16x8 L3 = bt[(33 * 5 + 3) * 64 + lane];
  bf16x8 L4 = bt[(33 * 5 + 4) * 64 + lane];
  float w2s = w2sum[0];
  float b2v = bm2[0];

#pragma unroll
  for (int s = 0; s < 4; ++s) {
    f32x4 accL = {0.f, 0.f, 0.f, 0.f};
    accL = __builtin_amdgcn_mfma_f32_16x16x32_bf16(A[s][0], L0, accL, 0, 0, 0);
    accL = __builtin_amdgcn_mfma_f32_16x16x32_bf16(A[s][1], L1, accL, 0, 0, 0);
    accL = __builtin_amdgcn_mfma_f32_16x16x32_bf16(A[s][2], L2, accL, 0, 0, 0);
    accL = __builtin_amdgcn_mfma_f32_16x16x32_bf16(A[s][3], L3, accL, 0, 0, 0);
    accL = __builtin_amdgcn_mfma_f32_16x16x32_bf16(A5[s],   L4, accL, 0, 0, 0);
    float ov[4] = {osum[s][0].x, osum[s][0].y, osum[s][1].x, osum[s][1].y};
#pragma unroll
    for (int r = 0; r < 4; ++r) {
      float lin = accL[r] + __shfl_xor(accL[r], 1);  // c_hi (m=0) + c_lo (m=1)
      float v = ov[r];
      v += __shfl_xor(v, 1);
      v += __shfl_xor(v, 2);
      v += __shfl_xor(v, 4);
      v += __shfl_xor(v, 8);
      if (m == 0) {
        int row = base + s * 16 + q * 4 + r;
        if (row < KE) out[row] = v - w2s + lin + b2v;
      }
    }
  }
}

extern "C" void kernel_launch(void* const* d_in, const int* in_sizes, int n_in,
                              void* d_out, int out_size, void* d_ws, size_t ws_size,
                              hipStream_t stream) {
  const float* pos  = (const float*)d_in[0];
  const int* eidx   = (const int*)d_in[1];
  const int* geidx  = (const int*)d_in[2];
  const float* eattr= (const float*)d_in[3];
  const float* W0   = (const float*)d_in[4];
  const float* as0  = (const float*)d_in[5];
  const float* ad0  = (const float*)d_in[6];
  const float* b0   = (const float*)d_in[7];
  const float* W1   = (const float*)d_in[8];
  const float* as1  = (const float*)d_in[9];
  const float* ad1  = (const float*)d_in[10];
  const float* b1   = (const float*)d_in[11];
  const float* Wm1  = (const float*)d_in[12];
  const float* bm1  = (const float*)d_in[13];
  const float* Wm2  = (const float*)d_in[14];
  const float* bm2  = (const float*)d_in[15];
  float* out = (float*)d_out;

  char* ws = (char*)d_ws;
  size_t off = 0;
  auto carve = [&](size_t bytes) {
    char* p = ws + off;
    off = (off + bytes + 255) & ~(size_t)255;
    return p;
  };
  int* counts    = (int*)carve((size_t)KN * 4);    // zeroed by memset below
  int* cursor    = (int*)carve((size_t)KN * 4);    // zeroed by memset below
  int* incl      = (int*)carve((size_t)KN * 4);
  int* row_start = (int*)carve((size_t)KN * 4);
  int* bsum      = (int*)carve(128 * 4);
  int* boff      = (int*)carve(128 * 4);
  int* csr_src   = (int*)carve((size_t)KEG * 4);
  u16* h         = (u16*)carve((size_t)KN * 64 * 2);
  u16* x12       = (u16*)carve((size_t)KN * 64 * 2);
  float* a_s     = (float*)carve((size_t)KN * 4);
  float* a_d     = (float*)carve((size_t)KN * 4);
  u16* wm1t      = (u16*)carve((size_t)36 * 5 * 512 * 2);  // tiles 34..35 = pad
  u16* w1t       = (u16*)carve((size_t)4 * 2 * 64 * 8 * 2);
  float2* wsc2   = (float2*)carve((size_t)33 * 64 * 8);
  float* w2sum   = (float*)carve(256);

  const int* gsrc = geidx;
  const int* gdst = geidx + KEG;

  // zero counts+cursor (contiguous at ws start: 400128 + 400000 bytes)
  hipMemsetAsync(d_ws, 0, 800128, stream);

  // fused front: prep + cvec + hist + transform0
  k_front<<<FB_PREP + FB_CVEC + FB_HIST + FB_T0, 256, 0, stream>>>(
      pos, W0, as0, ad0, Wm1, bm1, Wm2, W1, gdst,
      wm1t, w1t, wsc2, w2sum, counts, h, a_s, a_d);

  k_scan_block<<<NB, 1024, 0, stream>>>(counts, incl, bsum);
  k_scan_bsum<<<1, 64, 0, stream>>>(bsum, boff);
  k_scan_final<<<NB, 1024, 0, stream>>>(incl, counts, boff, row_start);
  k_fill<<<(KEG + 255) / 256, 256, 0, stream>>>(gsrc, gdst, row_start, cursor, csr_src);

  // ---- GAT layer 0 ----
  k_gat_agg<<<KN / 4, 256, 0, stream>>>(row_start, counts, csr_src, a_s, a_d, h, b0, x12);

  // ---- GAT layer 1 ----
  k_transform1<<<(KN + 63) / 64, 256, 0, stream>>>(x12, w1t, as1, ad1, h, a_s, a_d);
  k_gat_agg<<<KN / 4, 256, 0, stream>>>(row_start, counts, csr_src, a_s, a_d, h, b1, x12);

  // ---- fused edge MLP (async-LDS chunked double-buffer, f32 out) ----
  k_edge_mlp<<<(KE + 255) / 256, 256, 0, stream>>>(eidx, x12, eattr, wm1t, wsc2, w2sum, bm2, out);
}

// Round 14
// 386.013 us; speedup vs baseline: 1.1636x; 1.0124x over previous
//
#include <hip/hip_runtime.h>

#define KN 100000
#define KEG 600000
#define KE 600000
#define NB 98  // ceil(KN/1024) scan blocks
#define LOG2E 1.4426950408889634f
#define LN2 0.6931471805599453f

// k_front block ranges
#define FB_PREP 391
#define FB_CVEC 33
#define FB_HIST 2344
#define FB_T0 25000

using u16 = unsigned short;
typedef __bf16 bf16x8 __attribute__((ext_vector_type(8)));
typedef float f32x4 __attribute__((ext_vector_type(4)));
typedef float f32x2 __attribute__((ext_vector_type(2)));

__device__ __forceinline__ float b2f(u16 u) { return __uint_as_float(((unsigned)u) << 16); }
__device__ __forceinline__ u16 f2b(float f) {
  unsigned u = __float_as_uint(f);
  u += 0x7FFF + ((u >> 16) & 1);  // round-to-nearest-even
  return (u16)(u >> 16);
}
__device__ __forceinline__ int imin(int a, int b) { return a < b ? a : b; }
__device__ __forceinline__ float fexp2(float x) {
#if __has_builtin(__builtin_amdgcn_exp2f)
  return __builtin_amdgcn_exp2f(x);
#else
  return __expf(x * LN2);
#endif
}

// async global->LDS 16B copy (no VGPR round-trip). LDS dest is wave-uniform
// base + lane*16; callers pass per-lane pointers laid out exactly that way.
__device__ __forceinline__ void gload_lds16(const void* g, void* l) {
  __builtin_amdgcn_global_load_lds(
      (const __attribute__((address_space(1))) unsigned int*)g,
      (__attribute__((address_space(3))) unsigned int*)l,
      16, 0, 0);
}

// ---------------- fused front: prep + cvec + hist + transform0 ----------------
// wm1t: 36 tiles x 5 frags x 512 (tiles 34..35 = staging pad, never computed).
// Tiles 0..32: Wm1 rows 0..127 (frags 0..3) and K-ext rows [w128,w129,bm1]
// (frag 4), ALL x LOG2E. Tile 33 (owned by cvec range): linear composite
// c=B160@wm2 natural units, c_hi col0 / c_lo col1.
__global__ __launch_bounds__(256) void k_front(
    const float* __restrict__ pos, const float* __restrict__ W0,
    const float* __restrict__ att_s, const float* __restrict__ att_d,
    const float* __restrict__ wm1, const float* __restrict__ bm1,
    const float* __restrict__ wm2, const float* __restrict__ w1,
    const int* __restrict__ gdst,
    u16* __restrict__ wm1t, u16* __restrict__ w1t, float2* __restrict__ wsc2,
    float* __restrict__ w2sum, int* __restrict__ counts,
    u16* __restrict__ h, float* __restrict__ a_s, float* __restrict__ a_d) {
  int bid = blockIdx.x;
  if (bid < FB_PREP) {
    int idx = bid * 256 + threadIdx.x;
    if (idx < 33 * 5 * 512) {  // tiles 0..32 only
      int j = idx & 7;
      int lane = (idx >> 3) & 63;
      int f = (idx >> 9) % 5;
      int nt = idx / (512 * 5);
      int n = nt * 16 + (lane & 15);
      float v = 0.f;
      if (n < 520) {
        if (f < 4) {
          int k = f * 32 + (lane >> 4) * 8 + j;
          v = wm1[k * 520 + n] * LOG2E;
        } else {
          int kk = (lane >> 4) * 8 + j;
          if (kk == 0) v = wm1[128 * 520 + n] * LOG2E;
          else if (kk == 1) v = wm1[129 * 520 + n] * LOG2E;
          else if (kk == 2) v = bm1[n] * LOG2E;
        }
      }
      wm1t[idx] = f2b(v);
    }
    if (idx < 33 * 64) {
      int lane = idx & 63, nt = idx >> 6;
      int col = nt * 16 + (lane & 15);
      float w2 = (col < 520) ? wm2[col] : 0.f;
      float2 p; p.x = w2; p.y = -LN2 * w2;
      wsc2[idx] = p;
    }
    if (idx < 4 * 2 * 64 * 8) {  // W1 -> MFMA B frags
      int j = idx & 7;
      int lane = (idx >> 3) & 63;
      int kt = (idx >> 9) & 1;
      int nt = idx >> 10;
      int n = nt * 16 + (lane & 15);
      int k = kt * 32 + (lane >> 4) * 8 + j;
      w1t[idx] = f2b(w1[k * 64 + n]);
    }
  } else if (bid < FB_PREP + FB_CVEC) {
    // cvec: c_k = sum_h B160[k][h]*wm2[h]; w = row index 0..130; w==131 -> w2sum
    int lane = threadIdx.x & 63;
    int w = (bid - FB_PREP) * 4 + (threadIdx.x >> 6);
    float x = 0.f;
    if (w <= 129) {
      const float* row = wm1 + (size_t)w * 520;
#pragma unroll
      for (int j = 0; j < 8; ++j) x += row[j * 64 + lane] * wm2[j * 64 + lane];
      if (lane < 8) x += row[512 + lane] * wm2[512 + lane];
    } else if (w == 130) {
#pragma unroll
      for (int j = 0; j < 8; ++j) x += bm1[j * 64 + lane] * wm2[j * 64 + lane];
      if (lane < 8) x += bm1[512 + lane] * wm2[512 + lane];
    } else if (w == 131) {
#pragma unroll
      for (int j = 0; j < 8; ++j) x += wm2[j * 64 + lane];
      if (lane < 8) x += wm2[512 + lane];
    }
    for (int off = 1; off < 64; off <<= 1) x += __shfl_xor(x, off);
    if (w <= 130 && lane < 16) {
      int f = w >> 5, kk = w & 31;
      int qq = kk >> 3, jj = kk & 7;
      u16 chi = f2b(x);
      float v = (lane == 0) ? x : (lane == 1 ? (x - b2f(chi)) : 0.f);
      wm1t[(33 * 5 + f) * 512 + (qq * 16 + lane) * 8 + jj] = f2b(v);
    } else if (w == 131 && lane == 0) {
      w2sum[0] = x;
    }
  } else if (bid < FB_PREP + FB_CVEC + FB_HIST) {
    int e = (bid - (FB_PREP + FB_CVEC)) * 256 + threadIdx.x;
    if (e < KEG) atomicAdd(counts + gdst[e], 1);
  } else {
    // transform0: h = pos @ W0, a_s/a_d reductions. 25000 blocks x 4 nodes.
    int lane = threadIdx.x & 63;
    int n = (bid - (FB_PREP + FB_CVEC + FB_HIST)) * 4 + (threadIdx.x >> 6);
    float p0 = pos[n * 3 + 0], p1 = pos[n * 3 + 1], p2 = pos[n * 3 + 2];
    float hv = p0 * W0[lane] + p1 * W0[64 + lane] + p2 * W0[128 + lane];
    h[n * 64 + lane] = f2b(hv);
    float s = hv * att_s[lane];
    float d = hv * att_d[lane];
    for (int off = 1; off < 64; off <<= 1) { s += __shfl_xor(s, off); d += __shfl_xor(d, off); }
    if (lane == 0) { a_s[n] = s; a_d[n] = d; }
  }
}

// ---------------- CSR build ----------------

__global__ __launch_bounds__(1024) void k_scan_block(
    const int* __restrict__ counts, int* __restrict__ incl, int* __restrict__ bsum) {
  int gid = blockIdx.x * 1024 + threadIdx.x;
  int lane = threadIdx.x & 63, w = threadIdx.x >> 6;
  int x = (gid < KN) ? counts[gid] : 0;
  for (int off = 1; off < 64; off <<= 1) {
    int y = __shfl_up(x, off);
    if (lane >= off) x += y;
  }
  __shared__ int wtot[16];
  if (lane == 63) wtot[w] = x;
  __syncthreads();
  if (w == 0 && lane < 16) {
    int t = wtot[lane];
    for (int off = 1; off < 16; off <<= 1) {
      int y = __shfl_up(t, off);
      if (lane >= off) t += y;
    }
    wtot[lane] = t;
  }
  __syncthreads();
  if (w > 0) x += wtot[w - 1];
  if (gid < KN) incl[gid] = x;
  if (threadIdx.x == 1023) bsum[blockIdx.x] = x;
}

__global__ __launch_bounds__(64) void k_scan_bsum(const int* __restrict__ bsum, int* __restrict__ boff) {
  int lane = threadIdx.x;
  int x0 = (lane < NB) ? bsum[lane] : 0;
  int x1 = (64 + lane < NB) ? bsum[64 + lane] : 0;
  int i0 = x0, i1 = x1;
  for (int off = 1; off < 64; off <<= 1) {
    int y0 = __shfl_up(i0, off), y1 = __shfl_up(i1, off);
    if (lane >= off) { i0 += y0; i1 += y1; }
  }
  int tot0 = __shfl(i0, 63);
  if (lane < NB) boff[lane] = i0 - x0;
  if (64 + lane < NB) boff[64 + lane] = i1 - x1 + tot0;
}

__global__ __launch_bounds__(1024) void k_scan_final(
    const int* __restrict__ incl, const int* __restrict__ counts,
    const int* __restrict__ boff, int* __restrict__ row_start) {
  int gid = blockIdx.x * 1024 + threadIdx.x;
  if (gid < KN) row_start[gid] = incl[gid] - counts[gid] + boff[blockIdx.x];
}

// fill CSR: one atomic + ONE scattered 4B store per edge.
__global__ __launch_bounds__(256) void k_fill(
    const int* __restrict__ gsrc, const int* __restrict__ gdst,
    const int* __restrict__ row_start, int* __restrict__ cursor,
    int* __restrict__ csr_src) {
  int e = blockIdx.x * 256 + threadIdx.x;
  if (e >= KEG) return;
  int d = gdst[e];
  int pos = atomicAdd(cursor + d, 1);
  csr_src[row_start[d] + pos] = gsrc[e];
}

// ---------------- GAT layers ----------------

// FUSED agg(L0) + transform1: block = 64 nodes, wave = 16 nodes.
// Phase A: scatter-softmax aggregate of layer 0 (weights inline) -> x1 rows in
// LDS (row pad +8 u16 -> 2-way bank aliasing only). Phase B: h1 = x1 @ W1 via
// MFMA + fused a_s1/a_d1. Phase B consumes only this wave's own rows -> NO
// barrier. x1 never touches global memory.
__global__ __launch_bounds__(256) void k_aggt1(
    const int* __restrict__ row_start, const int* __restrict__ counts,
    const int* __restrict__ csr_src, const float* __restrict__ a_s0,
    const float* __restrict__ a_d0, const u16* __restrict__ h0,
    const float* __restrict__ b0, const u16* __restrict__ w1t,
    const float* __restrict__ as1, const float* __restrict__ ad1,
    u16* __restrict__ h1, float* __restrict__ a_s1, float* __restrict__ a_d1) {
  __shared__ u16 xb[64][72];  // 64 rows x (64 + 8 pad) bf16 = 9216 B
  int lane = threadIdx.x & 63;
  int wave = threadIdx.x >> 6;
  int nb = blockIdx.x * 64;  // grid 1563 -> nodes 0..100031, guarded
  int nodebase = nb + wave * 16;

  // ---- phase A: aggregate 16 nodes (lane = channel) ----
  for (int i = 0; i < 16; ++i) {
    int n = nodebase + i;
    float v = 0.f;
    if (n < KN) {
      int start = row_start[n], deg = counts[n];
      float adn = a_d0[n];
      float acc = 0.f, den = 0.f;
      int j = 0;
      for (; j + 4 <= deg; j += 4) {
        int s0 = csr_src[start + j];
        int s1 = csr_src[start + j + 1];
        int s2 = csr_src[start + j + 2];
        int s3 = csr_src[start + j + 3];
        float al0 = a_s0[s0] + adn; al0 = al0 > 0.f ? al0 : 0.2f * al0;
        float al1 = a_s0[s1] + adn; al1 = al1 > 0.f ? al1 : 0.2f * al1;
        float al2 = a_s0[s2] + adn; al2 = al2 > 0.f ? al2 : 0.2f * al2;
        float al3 = a_s0[s3] + adn; al3 = al3 > 0.f ? al3 : 0.2f * al3;
        float w0 = __expf(al0), w1 = __expf(al1);
        float w2 = __expf(al2), w3 = __expf(al3);
        float h0v = b2f(h0[s0 * 64 + lane]);
        float h1v = b2f(h0[s1 * 64 + lane]);
        float h2v = b2f(h0[s2 * 64 + lane]);
        float h3v = b2f(h0[s3 * 64 + lane]);
        den += (w0 + w1) + (w2 + w3);
        acc += w0 * h0v + w1 * h1v + w2 * h2v + w3 * h3v;
      }
      for (; j < deg; ++j) {
        int s0 = csr_src[start + j];
        float al = a_s0[s0] + adn; al = al > 0.f ? al : 0.2f * al;
        float w0 = __expf(al);
        den += w0;
        acc += w0 * b2f(h0[s0 * 64 + lane]);
      }
      v = acc / (den + 1e-16f) + b0[lane];
      v = v > 0.f ? v : expm1f(v);
    }
    xb[wave * 16 + i][lane] = f2b(v);
  }
  // no __syncthreads: phase B reads only rows written by this wave

  // ---- phase B: transform1 on these 16 nodes (MFMA from LDS) ----
  int m = lane & 15, q = lane >> 4;
  const u16* row = xb[wave * 16 + m];
  bf16x8 A0 = *(const bf16x8*)(row + q * 8);       // k 0..31
  bf16x8 A1 = *(const bf16x8*)(row + 32 + q * 8);  // k 32..63

  const bf16x8* bt = (const bf16x8*)w1t;
  float ps[4] = {0.f, 0.f, 0.f, 0.f};
  float pd[4] = {0.f, 0.f, 0.f, 0.f};
#pragma unroll
  for (int nt = 0; nt < 4; ++nt) {
    int col = nt * 16 + m;
    float asv = as1[col], adv = ad1[col];
    f32x4 acc = {0.f, 0.f, 0.f, 0.f};
    acc = __builtin_amdgcn_mfma_f32_16x16x32_bf16(A0, bt[(nt * 2 + 0) * 64 + lane], acc, 0, 0, 0);
    acc = __builtin_amdgcn_mfma_f32_16x16x32_bf16(A1, bt[(nt * 2 + 1) * 64 + lane], acc, 0, 0, 0);
#pragma unroll
    for (int r = 0; r < 4; ++r) {  // C/D: col=lane&15, row(node)=q*4+r
      int rown = nodebase + q * 4 + r;
      if (rown < KN) h1[rown * 64 + col] = f2b(acc[r]);
      ps[r] += acc[r] * asv;
      pd[r] += acc[r] * adv;
    }
  }
#pragma unroll
  for (int r = 0; r < 4; ++r) {
    float s = ps[r], d = pd[r];
    s += __shfl_xor(s, 1); d += __shfl_xor(d, 1);
    s += __shfl_xor(s, 2); d += __shfl_xor(d, 2);
    s += __shfl_xor(s, 4); d += __shfl_xor(d, 4);
    s += __shfl_xor(s, 8); d += __shfl_xor(d, 8);
    int rown = nodebase + q * 4 + r;
    if (m == 0 && rown < KN) { a_s1[rown] = s; a_d1[rown] = d; }
  }
}

// aggregate layer 1 (weights inline, 4-way ILP) -> x12 bf16 global.
__global__ __launch_bounds__(256) void k_gat_agg(
    const int* __restrict__ row_start, const int* __restrict__ counts,
    const int* __restrict__ csr_src, const float* __restrict__ a_s,
    const float* __restrict__ a_d, const u16* __restrict__ h,
    const float* __restrict__ bias, u16* __restrict__ xout) {
  int lane = threadIdx.x & 63;
  int n = blockIdx.x * 4 + (threadIdx.x >> 6);  // grid covers KN exactly
  int start = row_start[n], deg = counts[n];
  float adn = a_d[n];
  float acc = 0.f, den = 0.f;
  int j = 0;
  for (; j + 4 <= deg; j += 4) {
    int s0 = csr_src[start + j];
    int s1 = csr_src[start + j + 1];
    int s2 = csr_src[start + j + 2];
    int s3 = csr_src[start + j + 3];
    float al0 = a_s[s0] + adn; al0 = al0 > 0.f ? al0 : 0.2f * al0;
    float al1 = a_s[s1] + adn; al1 = al1 > 0.f ? al1 : 0.2f * al1;
    float al2 = a_s[s2] + adn; al2 = al2 > 0.f ? al2 : 0.2f * al2;
    float al3 = a_s[s3] + adn; al3 = al3 > 0.f ? al3 : 0.2f * al3;
    float w0 = __expf(al0), w1 = __expf(al1);
    float w2 = __expf(al2), w3 = __expf(al3);
    float h0 = b2f(h[s0 * 64 + lane]);
    float h1 = b2f(h[s1 * 64 + lane]);
    float h2 = b2f(h[s2 * 64 + lane]);
    float h3 = b2f(h[s3 * 64 + lane]);
    den += (w0 + w1) + (w2 + w3);
    acc += w0 * h0 + w1 * h1 + w2 * h2 + w3 * h3;
  }
  for (; j < deg; ++j) {
    int s0 = csr_src[start + j];
    float al = a_s[s0] + adn; al = al > 0.f ? al : 0.2f * al;
    float w0 = __expf(al);
    den += w0;
    acc += w0 * b2f(h[s0 * 64 + lane]);
  }
  float v = acc / (den + 1e-16f) + bias[lane];
  v = v > 0.f ? v : expm1f(v);
  xout[n * 64 + lane] = f2b(v);
}

// ---------------- edge MLP (R12 structure, unchanged) ----------------
__global__ __launch_bounds__(256) void k_edge_mlp(
    const int* __restrict__ eidx, const u16* __restrict__ x2bf,
    const float* __restrict__ eattr, const u16* __restrict__ wm1t,
    const float2* __restrict__ wsc2, const float* __restrict__ w2sum,
    const float* __restrict__ bm2, float* __restrict__ out) {
  __shared__ uint4 Bbuf[2][20 * 64];  // 40 KB
  int tid = threadIdx.x;
  int lane = tid & 63;
  int wave = tid >> 6;
  int base = blockIdx.x * 256 + wave * 64;
  int m = lane & 15, q = lane >> 4;

  const uint4* gB = (const uint4*)wm1t;  // chunk ch = uint4 [ch*1280, +1280)
#pragma unroll
  for (int k = 0; k < 5; ++k)
    gload_lds16(gB + tid + k * 256, &Bbuf[0][tid + k * 256]);

  bf16x8 A[4][4];
#pragma unroll
  for (int s = 0; s < 4; ++s) {
    int row = imin(base + s * 16 + m, KE - 1);
    int es = eidx[row], ed = eidx[KE + row];
    const bf16x8* psrc = (const bf16x8*)(x2bf + es * 64);
    const bf16x8* pdst = (const bf16x8*)(x2bf + ed * 64);
    A[s][0] = psrc[q];
    A[s][1] = psrc[q + 4];
    A[s][2] = pdst[q];
    A[s][3] = pdst[q + 4];
  }
  bf16x8 A5[4];
#pragma unroll
  for (int s = 0; s < 4; ++s) {
    bf16x8 a5 = {0, 0, 0, 0, 0, 0, 0, 0};
    if (q == 0) {
      int row = imin(base + s * 16 + m, KE - 1);
      a5[0] = (__bf16)eattr[row * 2 + 0];
      a5[1] = (__bf16)eattr[row * 2 + 1];
      a5[2] = (__bf16)1.0f;
    }
    A5[s] = a5;
  }

  f32x2 osum[4][2];
#pragma unroll
  for (int s = 0; s < 4; ++s) {
    osum[s][0] = (f32x2){0.f, 0.f};
    osum[s][1] = (f32x2){0.f, 0.f};
  }

  __syncthreads();  // chunk 0 landed

#pragma unroll 1
  for (int ch = 0; ch < 9; ++ch) {
    int cur = ch & 1, nxt = cur ^ 1;
    if (ch < 8) {
      const uint4* gs = gB + (ch + 1) * 1280;
#pragma unroll
      for (int k = 0; k < 5; ++k)
        gload_lds16(gs + tid + k * 256, &Bbuf[nxt][tid + k * 256]);
    }
    int lim = (ch == 8) ? 1 : 4;
#pragma unroll 1
    for (int li = 0; li < lim; ++li) {
      int nt = ch * 4 + li;
      const bf16x8* lb = (const bf16x8*)(Bbuf[cur] + li * 5 * 64);
      bf16x8 B0 = lb[0 * 64 + lane];
      bf16x8 B1 = lb[1 * 64 + lane];
      bf16x8 B2 = lb[2 * 64 + lane];
      bf16x8 B3 = lb[3 * 64 + lane];
      bf16x8 B4 = lb[4 * 64 + lane];
      float2 w2 = wsc2[nt * 64 + lane];
#pragma unroll
      for (int s = 0; s < 4; ++s) {
        f32x4 acc = {0.f, 0.f, 0.f, 0.f};
        acc = __builtin_amdgcn_mfma_f32_16x16x32_bf16(A[s][0], B0, acc, 0, 0, 0);
        acc = __builtin_amdgcn_mfma_f32_16x16x32_bf16(A[s][1], B1, acc, 0, 0, 0);
        acc = __builtin_amdgcn_mfma_f32_16x16x32_bf16(A[s][2], B2, acc, 0, 0, 0);
        acc = __builtin_amdgcn_mfma_f32_16x16x32_bf16(A[s][3], B3, acc, 0, 0, 0);
        acc = __builtin_amdgcn_mfma_f32_16x16x32_bf16(A5[s],   B4, acc, 0, 0, 0);
        f32x2 t0 = {fminf(acc[0], 0.f), fminf(acc[1], 0.f)};
        f32x2 t1 = {fminf(acc[2], 0.f), fminf(acc[3], 0.f)};
        f32x2 e0 = {fexp2(t0.x), fexp2(t0.y)};
        f32x2 e1 = {fexp2(t1.x), fexp2(t1.y)};
        osum[s][0] += e0 * w2.x + t0 * w2.y;
        osum[s][1] += e1 * w2.x + t1 * w2.y;
      }
    }
    if (ch < 8) __syncthreads();
  }

  const bf16x8* bt = (const bf16x8*)wm1t;
  bf16x8 L0 = bt[(33 * 5 + 0) * 64 + lane];
  bf16x8 L1 = bt[(33 * 5 + 1) * 64 + lane];
  bf16x8 L2 = bt[(33 * 5 + 2) * 64 + lane];
  bf16x8 L3 = bt[(33 * 5 + 3) * 64 + lane];
  bf16x8 L4 = bt[(33 * 5 + 4) * 64 + lane];
  float w2s = w2sum[0];
  float b2v = bm2[0];

#pragma unroll
  for (int s = 0; s < 4; ++s) {
    f32x4 accL = {0.f, 0.f, 0.f, 0.f};
    accL = __builtin_amdgcn_mfma_f32_16x16x32_bf16(A[s][0], L0, accL, 0, 0, 0);
    accL = __builtin_amdgcn_mfma_f32_16x16x32_bf16(A[s][1], L1, accL, 0, 0, 0);
    accL = __builtin_amdgcn_mfma_f32_16x16x32_bf16(A[s][2], L2, accL, 0, 0, 0);
    accL = __builtin_amdgcn_mfma_f32_16x16x32_bf16(A[s][3], L3, accL, 0, 0, 0);
    accL = __builtin_amdgcn_mfma_f32_16x16x32_bf16(A5[s],   L4, accL, 0, 0, 0);
    float ov[4] = {osum[s][0].x, osum[s][0].y, osum[s][1].x, osum[s][1].y};
#pragma unroll
    for (int r = 0; r < 4; ++r) {
      float lin = accL[r] + __shfl_xor(accL[r], 1);
      float v = ov[r];
      v += __shfl_xor(v, 1);
      v += __shfl_xor(v, 2);
      v += __shfl_xor(v, 4);
      v += __shfl_xor(v, 8);
      if (m == 0) {
        int row = base + s * 16 + q * 4 + r;
        if (row < KE) out[row] = v - w2s + lin + b2v;
      }
    }
  }
}

extern "C" void kernel_launch(void* const* d_in, const int* in_sizes, int n_in,
                              void* d_out, int out_size, void* d_ws, size_t ws_size,
                              hipStream_t stream) {
  const float* pos  = (const float*)d_in[0];
  const int* eidx   = (const int*)d_in[1];
  const int* geidx  = (const int*)d_in[2];
  const float* eattr= (const float*)d_in[3];
  const float* W0   = (const float*)d_in[4];
  const float* as0  = (const float*)d_in[5];
  const float* ad0  = (const float*)d_in[6];
  const float* b0   = (const float*)d_in[7];
  const float* W1   = (const float*)d_in[8];
  const float* as1  = (const float*)d_in[9];
  const float* ad1  = (const float*)d_in[10];
  const float* b1   = (const float*)d_in[11];
  const float* Wm1  = (const float*)d_in[12];
  const float* bm1  = (const float*)d_in[13];
  const float* Wm2  = (const float*)d_in[14];
  const float* bm2  = (const float*)d_in[15];
  float* out = (float*)d_out;

  char* ws = (char*)d_ws;
  size_t off = 0;
  auto carve = [&](size_t bytes) {
    char* p = ws + off;
    off = (off + bytes + 255) & ~(size_t)255;
    return p;
  };
  int* counts    = (int*)carve((size_t)KN * 4);    // zeroed by memset below
  int* cursor    = (int*)carve((size_t)KN * 4);    // zeroed by memset below
  int* incl      = (int*)carve((size_t)KN * 4);
  int* row_start = (int*)carve((size_t)KN * 4);
  int* bsum      = (int*)carve(128 * 4);
  int* boff      = (int*)carve(128 * 4);
  int* csr_src   = (int*)carve((size_t)KEG * 4);
  u16* h0        = (u16*)carve((size_t)KN * 64 * 2);
  u16* h1        = (u16*)carve((size_t)KN * 64 * 2);
  u16* x12       = (u16*)carve((size_t)KN * 64 * 2);
  float* a_s0    = (float*)carve((size_t)KN * 4);
  float* a_d0    = (float*)carve((size_t)KN * 4);
  float* a_s1    = (float*)carve((size_t)KN * 4);
  float* a_d1    = (float*)carve((size_t)KN * 4);
  u16* wm1t      = (u16*)carve((size_t)36 * 5 * 512 * 2);  // tiles 34..35 = pad
  u16* w1t       = (u16*)carve((size_t)4 * 2 * 64 * 8 * 2);
  float2* wsc2   = (float2*)carve((size_t)33 * 64 * 8);
  float* w2sum   = (float*)carve(256);

  const int* gsrc = geidx;
  const int* gdst = geidx + KEG;

  // zero counts+cursor (contiguous at ws start: 400128 + 400000 bytes)
  hipMemsetAsync(d_ws, 0, 800128, stream);

  // fused front: prep + cvec + hist + transform0 (layer-0 h/a_s/a_d)
  k_front<<<FB_PREP + FB_CVEC + FB_HIST + FB_T0, 256, 0, stream>>>(
      pos, W0, as0, ad0, Wm1, bm1, Wm2, W1, gdst,
      wm1t, w1t, wsc2, w2sum, counts, h0, a_s0, a_d0);

  k_scan_block<<<NB, 1024, 0, stream>>>(counts, incl, bsum);
  k_scan_bsum<<<1, 64, 0, stream>>>(bsum, boff);
  k_scan_final<<<NB, 1024, 0, stream>>>(incl, counts, boff, row_start);
  k_fill<<<(KEG + 255) / 256, 256, 0, stream>>>(gsrc, gdst, row_start, cursor, csr_src);

  // ---- fused GAT layer-0 aggregate + layer-1 transform ----
  k_aggt1<<<(KN + 63) / 64, 256, 0, stream>>>(row_start, counts, csr_src,
                                              a_s0, a_d0, h0, b0,
                                              w1t, as1, ad1, h1, a_s1, a_d1);

  // ---- GAT layer-1 aggregate ----
  k_gat_agg<<<KN / 4, 256, 0, stream>>>(row_start, counts, csr_src, a_s1, a_d1, h1, b1, x12);

  // ---- fused edge MLP (async-LDS chunked double-buffer, f32 out) ----
  k_edge_mlp<<<(KE + 255) / 256, 256, 0, stream>>>(eidx, x12, eattr, wm1t, wsc2, w2sum, bm2, out);
}